// Round 3
// baseline (4077.299 us; speedup 1.0000x reference)
//
#include <hip/hip_runtime.h>
#include <hip/hip_bf16.h>

#define NB 2
#define LL 2048
#define DD 512
#define HH 8
#define EE 64
#define DFF 1024
#define NL 4
#define EPS_F 1e-6f

typedef __bf16 bf16x8 __attribute__((ext_vector_type(8)));
typedef float f32x4 __attribute__((ext_vector_type(4)));

// round-to-nearest-even f32 -> bf16 bits
__device__ __forceinline__ unsigned short f2bf(float f) {
    unsigned int u = __float_as_uint(f);
    unsigned int r = (u + 0x7FFFu + ((u >> 16) & 1u)) >> 16;
    return (unsigned short)r;
}

// ---------------------------------------------------------------------------
// rope table: cos/sin of (l * 10000^(-i/32)) for l in [0,L), i in [0,32)
// ---------------------------------------------------------------------------
__global__ void rope_table_kernel(float* __restrict__ cosT, float* __restrict__ sinT) {
    int idx = blockIdx.x * 256 + threadIdx.x;
    if (idx >= LL * 32) return;
    int l = idx >> 5, i = idx & 31;
    float inv = powf(10000.f, -(float)i * (1.f / 32.f));
    float ang = (float)l * inv;
    cosT[idx] = cosf(ang);
    sinT[idx] = sinf(ang);
}

// ---------------------------------------------------------------------------
// weight cast + transpose: W[K,N] f32 -> WT[N,K] bf16 bits. 32x32 LDS tile.
// grid (N/32, K/32), 256 threads.
// ---------------------------------------------------------------------------
__global__ __launch_bounds__(256) void wcast_t_kernel(const float* __restrict__ W,
                                                      unsigned short* __restrict__ WT,
                                                      int K, int N) {
    __shared__ float tile[32][33];
    int n0 = blockIdx.x * 32, k0 = blockIdx.y * 32;
    int r = threadIdx.x >> 5, c = threadIdx.x & 31;
#pragma unroll
    for (int i = 0; i < 4; ++i)
        tile[r + 8 * i][c] = W[(size_t)(k0 + r + 8 * i) * N + n0 + c];
    __syncthreads();
#pragma unroll
    for (int i = 0; i < 4; ++i)
        WT[(size_t)(n0 + r + 8 * i) * K + k0 + c] = f2bf(tile[c][r + 8 * i]);
}

// ---------------------------------------------------------------------------
// s[b,d] = 1 + sum_k cond[b,k] * W[k,d]    (B*D = 1024 outputs, K = 512)
// ---------------------------------------------------------------------------
__global__ void cond_gemm_kernel(const float* __restrict__ cond,
                                 const float* __restrict__ W,
                                 float* __restrict__ out) {
    int idx = blockIdx.x * 256 + threadIdx.x;   // 0..1023
    int b = idx >> 9, d = idx & 511;
    const float* c = cond + b * DD;
    float s = 1.f;
#pragma unroll 8
    for (int k = 0; k < DD; ++k) s = fmaf(c[k], W[k * DD + d], s);
    out[idx] = s;
}

// ---------------------------------------------------------------------------
// RMSNorm over D=512, scale (B,D) per-batch, OUTPUT bf16 (packed uint stores)
// one block (256 thr) per row, 2 floats/thread
// ---------------------------------------------------------------------------
__global__ __launch_bounds__(256) void rmsnorm_bf16_kernel(const float* __restrict__ x,
                                                           const float* __restrict__ scale,
                                                           unsigned short* __restrict__ y) {
    int row = blockIdx.x;
    int b = row >> 11;
    int t = threadIdx.x;
    float2 v = ((const float2*)(x + (size_t)row * DD))[t];
    float ss = v.x * v.x + v.y * v.y;
#pragma unroll
    for (int o = 32; o > 0; o >>= 1) ss += __shfl_xor(ss, o);
    __shared__ float red[4];
    if ((t & 63) == 0) red[t >> 6] = ss;
    __syncthreads();
    float tot = red[0] + red[1] + red[2] + red[3];
    float inv = rsqrtf(tot * (1.f / DD) + EPS_F);
    float2 s2 = ((const float2*)(scale + b * DD))[t];
    unsigned int lo = f2bf(v.x * s2.x * inv);
    unsigned int hi = f2bf(v.y * s2.y * inv);
    ((unsigned int*)(y + (size_t)row * DD))[t] = lo | (hi << 16);
}

// RMSNorm, scale (D,), fp32 output (final layer)
__global__ __launch_bounds__(256) void rmsnorm_f32_kernel(const float* __restrict__ x,
                                                          const float* __restrict__ scale,
                                                          float* __restrict__ y) {
    int row = blockIdx.x;
    int t = threadIdx.x;
    float2 v = ((const float2*)(x + (size_t)row * DD))[t];
    float ss = v.x * v.x + v.y * v.y;
#pragma unroll
    for (int o = 32; o > 0; o >>= 1) ss += __shfl_xor(ss, o);
    __shared__ float red[4];
    if ((t & 63) == 0) red[t >> 6] = ss;
    __syncthreads();
    float tot = red[0] + red[1] + red[2] + red[3];
    float inv = rsqrtf(tot * (1.f / DD) + EPS_F);
    float2 s2 = ((const float2*)scale)[t];
    float2 o2;
    o2.x = v.x * s2.x * inv;
    o2.y = v.y * s2.y * inv;
    ((float2*)(y + (size_t)row * DD))[t] = o2;
}

// ---------------------------------------------------------------------------
// bf16 MFMA GEMM: C[M,N] = (R?R:0) + A[M,K] @ BT[N,K]^T
// 128x128 tile, BK=32, 256 thr = 4 waves, each wave 64x64 (4x4 16x16 frags).
// LDS rows padded to 40 bf16 (80B) -> 2-way bank alias on ds_read_b128 (free).
// ---------------------------------------------------------------------------
#define LDP 40
__global__ __launch_bounds__(256) void gemm_bf16_kernel(const unsigned short* __restrict__ A,
                                                        const unsigned short* __restrict__ BT,
                                                        const float* __restrict__ R,
                                                        float* __restrict__ C,
                                                        int M, int N, int K) {
    __shared__ unsigned short As[128 * LDP];
    __shared__ unsigned short Bs[128 * LDP];
    int tid = threadIdx.x;
    int n0 = blockIdx.x * 128, m0 = blockIdx.y * 128;
    int w = tid >> 6, l = tid & 63;
    int wr = w >> 1, wc = w & 1;            // wave tile origin (wr*64, wc*64)
    int kf = 8 * (l >> 4);                  // k offset of this lane's fragment
    int rf = l & 15;                        // m (or n) index within 16

    f32x4 acc[4][4] = {};

    for (int k0 = 0; k0 < K; k0 += 32) {
        // stage A,B tiles: 128 rows x 32 bf16 each; thread t copies 2x16B per tile
#pragma unroll
        for (int u2 = 0; u2 < 2; ++u2) {
            int c = tid * 2 + u2;           // 16B-chunk id, 0..511
            int row = c >> 2, ch = c & 3;   // 4 chunks per 64B row
            uint4 av = *(const uint4*)(A + (size_t)(m0 + row) * K + k0 + ch * 8);
            *(uint4*)(&As[row * LDP + ch * 8]) = av;
            uint4 bv = *(const uint4*)(BT + (size_t)(n0 + row) * K + k0 + ch * 8);
            *(uint4*)(&Bs[row * LDP + ch * 8]) = bv;
        }
        __syncthreads();

        bf16x8 a[4], b[4];
#pragma unroll
        for (int i = 0; i < 4; ++i)
            a[i] = *(const bf16x8*)(&As[(wr * 64 + i * 16 + rf) * LDP + kf]);
#pragma unroll
        for (int j = 0; j < 4; ++j)
            b[j] = *(const bf16x8*)(&Bs[(wc * 64 + j * 16 + rf) * LDP + kf]);
#pragma unroll
        for (int i = 0; i < 4; ++i)
#pragma unroll
            for (int j = 0; j < 4; ++j)
                acc[i][j] = __builtin_amdgcn_mfma_f32_16x16x32_bf16(a[i], b[j], acc[i][j], 0, 0, 0);
        __syncthreads();
    }

    // C/D layout (HW-verified): col = lane&15, row = (lane>>4)*4 + reg
    int rl = l >> 4, cl = l & 15;
#pragma unroll
    for (int i = 0; i < 4; ++i)
#pragma unroll
        for (int j = 0; j < 4; ++j)
#pragma unroll
            for (int r = 0; r < 4; ++r) {
                int row = m0 + wr * 64 + i * 16 + rl * 4 + r;
                int col = n0 + wc * 64 + j * 16 + cl;
                size_t off = (size_t)row * N + col;
                float v = acc[i][j][r];
                if (R) v += R[off];
                C[off] = v;
            }
}

// ---------------------------------------------------------------------------
// per-head RMSNorm (scalar hs from qk_scale) + rope for q,k; pass-through v.
// One wave per (b,l,h); lane = e. Writes (B,H,L,E) layout, fp32.
// ---------------------------------------------------------------------------
__global__ __launch_bounds__(256) void qknorm_rope_kernel(const float* __restrict__ qkv,
                                                          const float* __restrict__ qs,
                                                          const float* __restrict__ cosT,
                                                          const float* __restrict__ sinT,
                                                          float* __restrict__ qh,
                                                          float* __restrict__ kh,
                                                          float* __restrict__ vh) {
    int w = blockIdx.x * 4 + (threadIdx.x >> 6);   // (b*L + l)*H + h
    int e = threadIdx.x & 63;
    int h = w & 7;
    int l = (w >> 3) & (LL - 1);
    int b = w >> 14;
    size_t rb = ((size_t)(b * LL + l)) * (3 * DD) + h * EE + e;
    float q = qkv[rb];
    float k = qkv[rb + DD];
    float v = qkv[rb + 2 * DD];
    float sq = q * q, sk = k * k;
#pragma unroll
    for (int o = 1; o < 64; o <<= 1) {
        sq += __shfl_xor(sq, o);
        sk += __shfl_xor(sk, o);
    }
    float hsc = expf(0.5f * fminf(qs[h], 4.60517019f) - 1.03972077f);
    float qn = q * hsc * rsqrtf(sq * (1.f / EE) + EPS_F);
    float kn = k * hsc * rsqrtf(sk * (1.f / EE) + EPS_F);
    float qp = __shfl_xor(qn, 32);
    float kp = __shfl_xor(kn, 32);
    int i = e & 31;
    float c = cosT[l * 32 + i], s = sinT[l * 32 + i];
    float qo = (e < 32) ? (qn * c - qp * s) : (qp * s + qn * c);
    float ko = (e < 32) ? (kn * c - kp * s) : (kp * s + kn * c);
    size_t ob = ((size_t)((b * HH + h) * LL + l)) * EE + e;
    qh[ob] = qo;
    kh[ob] = ko;
    vh[ob] = v;
}

// ---------------------------------------------------------------------------
// flash attention, fp32 math. One block (128 thr) per (b,h,128 q rows).
// Output written as bf16 bits into oh[(b*L+row)*D + h*E ...]
// ---------------------------------------------------------------------------
__global__ __launch_bounds__(128) void flash_attn_kernel(const float* __restrict__ qh,
                                                         const float* __restrict__ kh,
                                                         const float* __restrict__ vh,
                                                         unsigned short* __restrict__ oh) {
    __shared__ float Ks[32][64];
    __shared__ float Vs[32][64];
    int bid = blockIdx.x;            // 256 blocks
    int qb = bid & 15;
    int h = (bid >> 4) & 7;
    int b = bid >> 7;
    int t = threadIdx.x;
    int bh = b * HH + h;
    int row = qb * 128 + t;

    const float4* qptr = (const float4*)(qh + ((size_t)bh * LL + row) * EE);
    float qreg[64];
#pragma unroll
    for (int j = 0; j < 16; ++j) {
        float4 v4 = qptr[j];
        qreg[4 * j + 0] = v4.x; qreg[4 * j + 1] = v4.y;
        qreg[4 * j + 2] = v4.z; qreg[4 * j + 3] = v4.w;
    }
    float oacc[64] = {};
    float m = -1e30f, lsum = 0.f;

    for (int kt = 0; kt < LL / 32; ++kt) {
        const float4* ksrc = (const float4*)(kh + ((size_t)bh * LL + kt * 32) * EE);
        const float4* vsrc = (const float4*)(vh + ((size_t)bh * LL + kt * 32) * EE);
        float4* kd = (float4*)&Ks[0][0];
        float4* vd = (float4*)&Vs[0][0];
#pragma unroll
        for (int j = 0; j < 4; ++j) {
            kd[t + j * 128] = ksrc[t + j * 128];
            vd[t + j * 128] = vsrc[t + j * 128];
        }
        __syncthreads();

        float sc[32];
#pragma unroll
        for (int kk = 0; kk < 32; ++kk) {
            float s = 0.f;
#pragma unroll
            for (int j = 0; j < 16; ++j) {
                float4 k4 = *(const float4*)&Ks[kk][4 * j];
                s = fmaf(qreg[4 * j + 0], k4.x, s);
                s = fmaf(qreg[4 * j + 1], k4.y, s);
                s = fmaf(qreg[4 * j + 2], k4.z, s);
                s = fmaf(qreg[4 * j + 3], k4.w, s);
            }
            sc[kk] = s * 0.125f;
        }
        float tm = sc[0];
#pragma unroll
        for (int kk = 1; kk < 32; ++kk) tm = fmaxf(tm, sc[kk]);
        float mnew = fmaxf(m, tm);
        float corr = expf(m - mnew);
        lsum *= corr;
#pragma unroll
        for (int ee = 0; ee < 64; ++ee) oacc[ee] *= corr;
#pragma unroll
        for (int kk = 0; kk < 32; ++kk) {
            float p = expf(sc[kk] - mnew);
            lsum += p;
#pragma unroll
            for (int j = 0; j < 16; ++j) {
                float4 v4 = *(const float4*)&Vs[kk][4 * j];
                oacc[4 * j + 0] = fmaf(p, v4.x, oacc[4 * j + 0]);
                oacc[4 * j + 1] = fmaf(p, v4.y, oacc[4 * j + 1]);
                oacc[4 * j + 2] = fmaf(p, v4.z, oacc[4 * j + 2]);
                oacc[4 * j + 3] = fmaf(p, v4.w, oacc[4 * j + 3]);
            }
        }
        m = mnew;
        __syncthreads();
    }
    float inv = 1.f / lsum;
    unsigned short* optr = oh + ((size_t)(b * LL + row)) * DD + h * EE;
#pragma unroll
    for (int j = 0; j < 16; ++j) {
        ushort4 s4;
        s4.x = f2bf(oacc[4 * j + 0] * inv);
        s4.y = f2bf(oacc[4 * j + 1] * inv);
        s4.z = f2bf(oacc[4 * j + 2] * inv);
        s4.w = f2bf(oacc[4 * j + 3] * inv);
        *(ushort4*)(optr + 4 * j) = s4;
    }
}

// ---------------------------------------------------------------------------
// geglu: g[r,j] = bf16( u[r,j] * gelu_exact(u[r, DFF + j]) )
// ---------------------------------------------------------------------------
__global__ void geglu_kernel(const float* __restrict__ u, unsigned short* __restrict__ g) {
    int idx = blockIdx.x * 256 + threadIdx.x;   // B*L*DFF = 4,194,304
    int r = idx >> 10, j = idx & 1023;
    float a = u[(size_t)r * (2 * DFF) + j];
    float x = u[(size_t)r * (2 * DFF) + DFF + j];
    float ge = 0.5f * x * (1.f + erff(x * 0.70710678f));
    g[idx] = f2bf(a * ge);
}

// ---------------------------------------------------------------------------
extern "C" void kernel_launch(void* const* d_in, const int* in_sizes, int n_in,
                              void* d_out, int out_size, void* d_ws, size_t ws_size,
                              hipStream_t stream) {
    const float* x        = (const float*)d_in[0];
    const float* cond     = (const float*)d_in[1];
    // d_in[2] attn_mask: bias varies only with query index -> softmax-invariant -> unused
    const float* wn_attn  = (const float*)d_in[3];
    const float* wqkv     = (const float*)d_in[4];
    const float* qk_scale = (const float*)d_in[5];
    const float* wout     = (const float*)d_in[6];
    const float* wn_ff    = (const float*)d_in[7];
    const float* wup      = (const float*)d_in[8];
    const float* wdown    = (const float*)d_in[9];
    const float* out_scale= (const float*)d_in[10];
    float* out = (float*)d_out;

    const int TOK = NB * LL;                 // 4096 rows
    const size_t nHx = (size_t)TOK * DD;     // 2,097,152

    float* ws = (float*)d_ws;
    // layout (float units):
    float* hx  = ws;                                  // [0, 2M)
    unsigned short* y_bf = (unsigned short*)(ws + 2097152);   // 2M ushorts in [2M,3M)
    float* big = ws + 3145728;                        // 8M floats [3M, 11M)
    float* qkv = big;                                 // 6M f32 (gemm-qkv .. qknorm)
    float* qh  = big + 6291456;                       // 2M f32 (qknorm .. flash)
    float* u   = big;                                 // 8M f32 (wup-gemm .. geglu)
    unsigned short* oh_bf = (unsigned short*)big;     // 2M ushorts (flash .. wout-gemm)
    float* kh  = ws + 11534336;                       // 2M f32
    unsigned short* g_bf = (unsigned short*)kh;       // 4M ushorts (geglu .. wdown-gemm)
    float* vh  = ws + 13631488;                       // 2M f32
    unsigned short* wt = (unsigned short*)(ws + 15728640);    // 10,485,760 ushorts
    unsigned short* wqkvT  = wt;                      // 4 x 1536*512
    unsigned short* woutT  = wt + 3145728;            // 4 x 512*512
    unsigned short* wupT   = wt + 4194304;            // 4 x 2048*512
    unsigned short* wdownT = wt + 8388608;            // 4 x 512*1024
    float* smal  = ws + 20971520;
    float* s_attn = smal;                             // 1024
    float* s_ff   = smal + 1024;                      // 1024
    float* cosT   = smal + 2048;                      // 65536
    float* sinT   = cosT + 65536;                     // 65536

    hipMemcpyAsync(hx, x, nHx * sizeof(float), hipMemcpyDeviceToDevice, stream);
    rope_table_kernel<<<256, 256, 0, stream>>>(cosT, sinT);

    // cast + transpose all weights to bf16 WT[N,K]
    for (int layer = 0; layer < NL; ++layer) {
        wcast_t_kernel<<<dim3(1536 / 32, 512 / 32), 256, 0, stream>>>(
            wqkv + (size_t)layer * 512 * 1536, wqkvT + (size_t)layer * 1536 * 512, 512, 1536);
        wcast_t_kernel<<<dim3(512 / 32, 512 / 32), 256, 0, stream>>>(
            wout + (size_t)layer * 512 * 512, woutT + (size_t)layer * 512 * 512, 512, 512);
        wcast_t_kernel<<<dim3(2048 / 32, 512 / 32), 256, 0, stream>>>(
            wup + (size_t)layer * 512 * 2048, wupT + (size_t)layer * 2048 * 512, 512, 2048);
        wcast_t_kernel<<<dim3(512 / 32, 1024 / 32), 256, 0, stream>>>(
            wdown + (size_t)layer * 1024 * 512, wdownT + (size_t)layer * 512 * 1024, 1024, 512);
    }

    for (int layer = 0; layer < NL; ++layer) {
        const float* wn_a = wn_attn + (size_t)layer * DD * DD;
        const float* qs   = qk_scale + layer * HH;
        const float* wn_f = wn_ff + (size_t)layer * DD * DD;

        cond_gemm_kernel<<<4, 256, 0, stream>>>(cond, wn_a, s_attn);
        rmsnorm_bf16_kernel<<<TOK, 256, 0, stream>>>(hx, s_attn, y_bf);
        gemm_bf16_kernel<<<dim3(1536 / 128, TOK / 128), 256, 0, stream>>>(
            y_bf, wqkvT + (size_t)layer * 1536 * 512, nullptr, qkv, TOK, 1536, 512);
        qknorm_rope_kernel<<<TOK * HH / 4, 256, 0, stream>>>(qkv, qs, cosT, sinT, qh, kh, vh);
        flash_attn_kernel<<<NB * HH * (LL / 128), 128, 0, stream>>>(qh, kh, vh, oh_bf);
        gemm_bf16_kernel<<<dim3(512 / 128, TOK / 128), 256, 0, stream>>>(
            oh_bf, woutT + (size_t)layer * 512 * 512, hx, hx, TOK, 512, 512);

        cond_gemm_kernel<<<4, 256, 0, stream>>>(cond, wn_f, s_ff);
        rmsnorm_bf16_kernel<<<TOK, 256, 0, stream>>>(hx, s_ff, y_bf);
        gemm_bf16_kernel<<<dim3(2048 / 128, TOK / 128), 256, 0, stream>>>(
            y_bf, wupT + (size_t)layer * 2048 * 512, nullptr, u, TOK, 2048, 512);
        geglu_kernel<<<TOK * DFF / 256, 256, 0, stream>>>(u, g_bf);
        gemm_bf16_kernel<<<dim3(512 / 128, TOK / 128), 256, 0, stream>>>(
            g_bf, wdownT + (size_t)layer * 512 * 1024, hx, hx, TOK, 512, 1024);
    }
    rmsnorm_f32_kernel<<<TOK, 256, 0, stream>>>(hx, out_scale, out);
}

// Round 5
// 1506.246 us; speedup vs baseline: 2.7069x; 2.7069x over previous
//
#include <hip/hip_runtime.h>
#include <hip/hip_bf16.h>

#define NB 2
#define LL 2048
#define DD 512
#define HH 8
#define EE 64
#define DFF 1024
#define NL 4
#define EPS_F 1e-6f

typedef __bf16 bf16x8 __attribute__((ext_vector_type(8)));
typedef float f32x4 __attribute__((ext_vector_type(4)));

// round-to-nearest-even f32 -> bf16 bits
__device__ __forceinline__ unsigned short f2bf(float f) {
    unsigned int u = __float_as_uint(f);
    unsigned int r = (u + 0x7FFFu + ((u >> 16) & 1u)) >> 16;
    return (unsigned short)r;
}

// ---------------------------------------------------------------------------
// rope table
// ---------------------------------------------------------------------------
__global__ void rope_table_kernel(float* __restrict__ cosT, float* __restrict__ sinT) {
    int idx = blockIdx.x * 256 + threadIdx.x;
    if (idx >= LL * 32) return;
    int l = idx >> 5, i = idx & 31;
    float inv = powf(10000.f, -(float)i * (1.f / 32.f));
    float ang = (float)l * inv;
    cosT[idx] = cosf(ang);
    sinT[idx] = sinf(ang);
}

// ---------------------------------------------------------------------------
// weight cast + transpose: W[K,N] f32 -> WT[N,K] bf16 bits. 32x32 LDS tile.
// ---------------------------------------------------------------------------
__global__ __launch_bounds__(256) void wcast_t_kernel(const float* __restrict__ W,
                                                      unsigned short* __restrict__ WT,
                                                      int K, int N) {
    __shared__ float tile[32][33];
    int n0 = blockIdx.x * 32, k0 = blockIdx.y * 32;
    int r = threadIdx.x >> 5, c = threadIdx.x & 31;
#pragma unroll
    for (int i = 0; i < 4; ++i)
        tile[r + 8 * i][c] = W[(size_t)(k0 + r + 8 * i) * N + n0 + c];
    __syncthreads();
#pragma unroll
    for (int i = 0; i < 4; ++i)
        WT[(size_t)(n0 + r + 8 * i) * K + k0 + c] = f2bf(tile[c][r + 8 * i]);
}

// ---------------------------------------------------------------------------
// s[b,d] = 1 + cond[b,:] @ W[:,d]
// ---------------------------------------------------------------------------
__global__ void cond_gemm_kernel(const float* __restrict__ cond,
                                 const float* __restrict__ W,
                                 float* __restrict__ out) {
    int idx = blockIdx.x * 256 + threadIdx.x;
    int b = idx >> 9, d = idx & 511;
    const float* c = cond + b * DD;
    float s = 1.f;
#pragma unroll 8
    for (int k = 0; k < DD; ++k) s = fmaf(c[k], W[k * DD + d], s);
    out[idx] = s;
}

// ---------------------------------------------------------------------------
// RMSNorm over D=512, scale (B,D), bf16 output
// ---------------------------------------------------------------------------
__global__ __launch_bounds__(256) void rmsnorm_bf16_kernel(const float* __restrict__ x,
                                                           const float* __restrict__ scale,
                                                           unsigned short* __restrict__ y) {
    int row = blockIdx.x;
    int b = row >> 11;
    int t = threadIdx.x;
    float2 v = ((const float2*)(x + (size_t)row * DD))[t];
    float ss = v.x * v.x + v.y * v.y;
#pragma unroll
    for (int o = 32; o > 0; o >>= 1) ss += __shfl_xor(ss, o);
    __shared__ float red[4];
    if ((t & 63) == 0) red[t >> 6] = ss;
    __syncthreads();
    float tot = red[0] + red[1] + red[2] + red[3];
    float inv = rsqrtf(tot * (1.f / DD) + EPS_F);
    float2 s2 = ((const float2*)(scale + b * DD))[t];
    unsigned int lo = f2bf(v.x * s2.x * inv);
    unsigned int hi = f2bf(v.y * s2.y * inv);
    ((unsigned int*)(y + (size_t)row * DD))[t] = lo | (hi << 16);
}

// RMSNorm, scale (D,), fp32 output (final)
__global__ __launch_bounds__(256) void rmsnorm_f32_kernel(const float* __restrict__ x,
                                                          const float* __restrict__ scale,
                                                          float* __restrict__ y) {
    int row = blockIdx.x;
    int t = threadIdx.x;
    float2 v = ((const float2*)(x + (size_t)row * DD))[t];
    float ss = v.x * v.x + v.y * v.y;
#pragma unroll
    for (int o = 32; o > 0; o >>= 1) ss += __shfl_xor(ss, o);
    __shared__ float red[4];
    if ((t & 63) == 0) red[t >> 6] = ss;
    __syncthreads();
    float tot = red[0] + red[1] + red[2] + red[3];
    float inv = rsqrtf(tot * (1.f / DD) + EPS_F);
    float2 s2 = ((const float2*)scale)[t];
    float2 o2;
    o2.x = v.x * s2.x * inv;
    o2.y = v.y * s2.y * inv;
    ((float2*)(y + (size_t)row * DD))[t] = o2;
}

// ---------------------------------------------------------------------------
// bf16 MFMA GEMM: C[M,N] = (R?R:0) + A[M,K] @ BT[N,K]^T
// ---------------------------------------------------------------------------
#define LDP 40
__global__ __launch_bounds__(256) void gemm_bf16_kernel(const unsigned short* __restrict__ A,
                                                        const unsigned short* __restrict__ BT,
                                                        const float* __restrict__ R,
                                                        float* __restrict__ C,
                                                        int M, int N, int K) {
    __shared__ unsigned short As[128 * LDP];
    __shared__ unsigned short Bs[128 * LDP];
    int tid = threadIdx.x;
    int n0 = blockIdx.x * 128, m0 = blockIdx.y * 128;
    int w = tid >> 6, l = tid & 63;
    int wr = w >> 1, wc = w & 1;
    int kf = 8 * (l >> 4);
    int rf = l & 15;

    f32x4 acc[4][4] = {};

    for (int k0 = 0; k0 < K; k0 += 32) {
#pragma unroll
        for (int u2 = 0; u2 < 2; ++u2) {
            int c = tid * 2 + u2;
            int row = c >> 2, ch = c & 3;
            uint4 av = *(const uint4*)(A + (size_t)(m0 + row) * K + k0 + ch * 8);
            *(uint4*)(&As[row * LDP + ch * 8]) = av;
            uint4 bv = *(const uint4*)(BT + (size_t)(n0 + row) * K + k0 + ch * 8);
            *(uint4*)(&Bs[row * LDP + ch * 8]) = bv;
        }
        __syncthreads();

        bf16x8 a[4], b[4];
#pragma unroll
        for (int i = 0; i < 4; ++i)
            a[i] = *(const bf16x8*)(&As[(wr * 64 + i * 16 + rf) * LDP + kf]);
#pragma unroll
        for (int j = 0; j < 4; ++j)
            b[j] = *(const bf16x8*)(&Bs[(wc * 64 + j * 16 + rf) * LDP + kf]);
#pragma unroll
        for (int i = 0; i < 4; ++i)
#pragma unroll
            for (int j = 0; j < 4; ++j)
                acc[i][j] = __builtin_amdgcn_mfma_f32_16x16x32_bf16(a[i], b[j], acc[i][j], 0, 0, 0);
        __syncthreads();
    }

    int rl = l >> 4, cl = l & 15;
#pragma unroll
    for (int i = 0; i < 4; ++i)
#pragma unroll
        for (int j = 0; j < 4; ++j)
#pragma unroll
            for (int r = 0; r < 4; ++r) {
                int row = m0 + wr * 64 + i * 16 + rl * 4 + r;
                int col = n0 + wc * 64 + j * 16 + cl;
                size_t off = (size_t)row * N + col;
                float v = acc[i][j][r];
                if (R) v += R[off];
                C[off] = v;
            }
}

// ---------------------------------------------------------------------------
// per-head RMSNorm + rope for q,k; bf16 out. 1/sqrt(8) folded into q and k so
// QK^T needs no post-scale. One wave per (b,l,h); lane = e.
// ---------------------------------------------------------------------------
__global__ __launch_bounds__(256) void qknorm_rope_kernel(const float* __restrict__ qkv,
                                                          const float* __restrict__ qs,
                                                          const float* __restrict__ cosT,
                                                          const float* __restrict__ sinT,
                                                          unsigned short* __restrict__ qh,
                                                          unsigned short* __restrict__ kh) {
    int w = blockIdx.x * 4 + (threadIdx.x >> 6);   // (b*L + l)*H + h
    int e = threadIdx.x & 63;
    int h = w & 7;
    int l = (w >> 3) & (LL - 1);
    int b = w >> 14;
    size_t rb = ((size_t)(b * LL + l)) * (3 * DD) + h * EE + e;
    float q = qkv[rb];
    float k = qkv[rb + DD];
    float sq = q * q, sk = k * k;
#pragma unroll
    for (int o = 1; o < 64; o <<= 1) {
        sq += __shfl_xor(sq, o);
        sk += __shfl_xor(sk, o);
    }
    float hsc = expf(0.5f * fminf(qs[h], 4.60517019f) - 1.03972077f) * 0.35355339059f;
    float qn = q * hsc * rsqrtf(sq * (1.f / EE) + EPS_F);
    float kn = k * hsc * rsqrtf(sk * (1.f / EE) + EPS_F);
    float qp = __shfl_xor(qn, 32);
    float kp = __shfl_xor(kn, 32);
    int i = e & 31;
    float c = cosT[l * 32 + i], s = sinT[l * 32 + i];
    float qo = (e < 32) ? (qn * c - qp * s) : (qp * s + qn * c);
    float ko = (e < 32) ? (kn * c - kp * s) : (kp * s + kn * c);
    size_t ob = ((size_t)((b * HH + h) * LL + l)) * EE + e;
    qh[ob] = f2bf(qo);
    kh[ob] = f2bf(ko);
}

// ---------------------------------------------------------------------------
// V transpose: qkv v-slice f32 [l][e] -> vt bf16 [bh*64+e][l]. 64x64 tiles.
// ---------------------------------------------------------------------------
__global__ __launch_bounds__(256) void vtrans_kernel(const float* __restrict__ qkv,
                                                     unsigned short* __restrict__ vt) {
    __shared__ float tile[64][65];
    int bid = blockIdx.x;            // 512 = 16 bh * 32 ltiles
    int lt = bid & 31, bh = bid >> 5;
    int b = bh >> 3, h = bh & 7;
    int l0 = lt * 64;
    int t = threadIdx.x;
#pragma unroll
    for (int i = 0; i < 4; ++i) {
        int c = t + i * 256;                  // 0..1023
        int row = c >> 4, q4 = c & 15;
        float4 v4 = *(const float4*)(qkv + ((size_t)(b * LL + l0 + row)) * (3 * DD) + 2 * DD + h * EE + q4 * 4);
        tile[row][q4 * 4 + 0] = v4.x;
        tile[row][q4 * 4 + 1] = v4.y;
        tile[row][q4 * 4 + 2] = v4.z;
        tile[row][q4 * 4 + 3] = v4.w;
    }
    __syncthreads();
    int e = t >> 2, lc = t & 3;
    unsigned int* dst = (unsigned int*)(vt + ((size_t)(bh * EE + e)) * LL + l0 + lc * 16);
#pragma unroll
    for (int j2 = 0; j2 < 8; ++j2) {
        unsigned int lo = f2bf(tile[lc * 16 + 2 * j2][e]);
        unsigned int hi = f2bf(tile[lc * 16 + 2 * j2 + 1][e]);
        dst[j2] = lo | (hi << 16);
    }
}

// ---------------------------------------------------------------------------
// MFMA flash attention. Block = 256 thr = 4 waves; wave owns 32 q-rows.
// K_lds[kv][e], VT_lds[e][kv] 64x64 bf16 (rows padded to 72).
// S frag layout (HW-verified): col = lane&15, row = (lane>>4)*4 + reg.
// ---------------------------------------------------------------------------
#define KVB 64
__global__ __launch_bounds__(256) void flash_mfma_kernel(const unsigned short* __restrict__ qh,
                                                         const unsigned short* __restrict__ kh,
                                                         const unsigned short* __restrict__ vt,
                                                         unsigned short* __restrict__ oh) {
    __shared__ unsigned short K_lds[64 * 72];
    __shared__ unsigned short VT_lds[64 * 72];
    __shared__ unsigned short P_lds[4][32 * 72];
    int bid = blockIdx.x;            // 256
    int qb = bid & 15, h = (bid >> 4) & 7, b = bid >> 7;
    int bh = b * HH + h;
    int tid = threadIdx.x, w = tid >> 6, l = tid & 63;
    int lo = l & 15, hi4 = l >> 4;
    int q0 = qb * 128 + w * 32;

    const unsigned short* qbase = qh + ((size_t)bh * LL) * EE;
    bf16x8 qa[2][2];
#pragma unroll
    for (int i = 0; i < 2; ++i)
#pragma unroll
        for (int s = 0; s < 2; ++s)
            qa[i][s] = *(const bf16x8*)(qbase + (size_t)(q0 + i * 16 + lo) * EE + s * 32 + 8 * hi4);

    f32x4 oacc[2][4] = {};
    float mrow[2][4], lrow[2][4];
#pragma unroll
    for (int i = 0; i < 2; ++i)
#pragma unroll
        for (int r = 0; r < 4; ++r) { mrow[i][r] = -3.0e38f; lrow[i][r] = 0.f; }

    for (int kt = 0; kt < LL / KVB; ++kt) {
        int kv0 = kt * KVB;
#pragma unroll
        for (int u = 0; u < 2; ++u) {
            int c = tid + u * 256;            // 0..511
            int row = c >> 3, ch = c & 7;
            *(uint4*)&K_lds[row * 72 + ch * 8] =
                *(const uint4*)(kh + ((size_t)bh * LL + kv0 + row) * EE + ch * 8);
            *(uint4*)&VT_lds[row * 72 + ch * 8] =
                *(const uint4*)(vt + ((size_t)bh * EE + row) * LL + kv0 + ch * 8);
        }
        __syncthreads();

        // S = Q K^T (scale pre-folded)
        f32x4 S[2][4] = {};
#pragma unroll
        for (int nf = 0; nf < 4; ++nf) {
#pragma unroll
            for (int s = 0; s < 2; ++s) {
                bf16x8 kb = *(const bf16x8*)&K_lds[(nf * 16 + lo) * 72 + s * 32 + 8 * hi4];
                S[0][nf] = __builtin_amdgcn_mfma_f32_16x16x32_bf16(qa[0][s], kb, S[0][nf], 0, 0, 0);
                S[1][nf] = __builtin_amdgcn_mfma_f32_16x16x32_bf16(qa[1][s], kb, S[1][nf], 0, 0, 0);
            }
        }

        // online softmax; row owned by 16-lane group (lanes share hi4)
#pragma unroll
        for (int i = 0; i < 2; ++i) {
#pragma unroll
            for (int r = 0; r < 4; ++r) {
                float t0 = fmaxf(fmaxf(S[i][0][r], S[i][1][r]), fmaxf(S[i][2][r], S[i][3][r]));
#pragma unroll
                for (int d = 1; d < 16; d <<= 1) t0 = fmaxf(t0, __shfl_xor(t0, d));
                float mn = fmaxf(mrow[i][r], t0);
                float corr = expf(mrow[i][r] - mn);
                mrow[i][r] = mn;
                lrow[i][r] *= corr;
                float rs = 0.f;
#pragma unroll
                for (int nf = 0; nf < 4; ++nf) {
                    float p = expf(S[i][nf][r] - mn);
                    rs += p;
                    P_lds[w][(i * 16 + hi4 * 4 + r) * 72 + nf * 16 + lo] = f2bf(p);
                }
#pragma unroll
                for (int d = 1; d < 16; d <<= 1) rs += __shfl_xor(rs, d);
                lrow[i][r] += rs;
#pragma unroll
                for (int nf = 0; nf < 4; ++nf) oacc[i][nf][r] *= corr;
            }
        }

        // O += P V
#pragma unroll
        for (int s = 0; s < 2; ++s) {
            bf16x8 pa0 = *(const bf16x8*)&P_lds[w][(lo) * 72 + s * 32 + 8 * hi4];
            bf16x8 pa1 = *(const bf16x8*)&P_lds[w][(16 + lo) * 72 + s * 32 + 8 * hi4];
#pragma unroll
            for (int nf = 0; nf < 4; ++nf) {
                bf16x8 vb = *(const bf16x8*)&VT_lds[(nf * 16 + lo) * 72 + s * 32 + 8 * hi4];
                oacc[0][nf] = __builtin_amdgcn_mfma_f32_16x16x32_bf16(pa0, vb, oacc[0][nf], 0, 0, 0);
                oacc[1][nf] = __builtin_amdgcn_mfma_f32_16x16x32_bf16(pa1, vb, oacc[1][nf], 0, 0, 0);
            }
        }
        __syncthreads();
    }

#pragma unroll
    for (int i = 0; i < 2; ++i)
#pragma unroll
        for (int r = 0; r < 4; ++r) {
            float inv = 1.f / lrow[i][r];
            int row = q0 + i * 16 + hi4 * 4 + r;
            unsigned short* op = oh + ((size_t)(b * LL + row)) * DD + h * EE;
#pragma unroll
            for (int nf = 0; nf < 4; ++nf)
                op[nf * 16 + lo] = f2bf(oacc[i][nf][r] * inv);
        }
}

// ---------------------------------------------------------------------------
// geglu: g = bf16( a * gelu_exact(b) )
// ---------------------------------------------------------------------------
__global__ void geglu_kernel(const float* __restrict__ u, unsigned short* __restrict__ g) {
    int idx = blockIdx.x * 256 + threadIdx.x;
    int r = idx >> 10, j = idx & 1023;
    float a = u[(size_t)r * (2 * DFF) + j];
    float x = u[(size_t)r * (2 * DFF) + DFF + j];
    float ge = 0.5f * x * (1.f + erff(x * 0.70710678f));
    g[idx] = f2bf(a * ge);
}

// ---------------------------------------------------------------------------
extern "C" void kernel_launch(void* const* d_in, const int* in_sizes, int n_in,
                              void* d_out, int out_size, void* d_ws, size_t ws_size,
                              hipStream_t stream) {
    const float* x        = (const float*)d_in[0];
    const float* cond     = (const float*)d_in[1];
    // d_in[2] attn_mask: bias varies only with query index -> softmax-invariant -> unused
    const float* wn_attn  = (const float*)d_in[3];
    const float* wqkv     = (const float*)d_in[4];
    const float* qk_scale = (const float*)d_in[5];
    const float* wout     = (const float*)d_in[6];
    const float* wn_ff    = (const float*)d_in[7];
    const float* wup      = (const float*)d_in[8];
    const float* wdown    = (const float*)d_in[9];
    const float* out_scale= (const float*)d_in[10];
    float* out = (float*)d_out;

    const int TOK = NB * LL;                 // 4096
    const size_t nHx = (size_t)TOK * DD;     // 2,097,152
    const size_t M = 1024 * 1024;

    float* ws = (float*)d_ws;
    float* hx  = ws;                                   // [0, 2M) f32
    unsigned short* y_bf = (unsigned short*)(ws + 2 * M);      // [2M,3M) 2M ushort
    float* qkv = ws + 3 * M;                           // [3M, 9M) f32
    float* u   = ws + 3 * M;                           // [3M, 11M) f32 (aliases qkv, disjoint lifetime)
    unsigned short* qh_bf = (unsigned short*)(ws + 11 * M);    // [11M,12M) 2M ushort
    unsigned short* g_bf  = (unsigned short*)(ws + 11 * M);    // [11M,13M) 4M ushort (qh/kh dead by geglu)
    unsigned short* kh_bf = (unsigned short*)(ws + 12 * M);    // [12M,13M)
    unsigned short* vt_bf = (unsigned short*)(ws + 13 * M);    // [13M,14M)
    unsigned short* oh_bf = (unsigned short*)(ws + 14 * M);    // [14M,15M)
    unsigned short* wt = (unsigned short*)(ws + 15 * M);       // 10,485,760 ushort = 5M f32 -> [15M,20M)
    unsigned short* wqkvT  = wt;
    unsigned short* woutT  = wt + 3145728;
    unsigned short* wupT   = wt + 4194304;
    unsigned short* wdownT = wt + 8388608;
    float* smal  = ws + 20 * M;               // FIX: was 20709376, overlapped wdownT tail
    float* s_attn = smal;
    float* s_ff   = smal + 1024;
    float* cosT   = smal + 2048;
    float* sinT   = cosT + 65536;

    hipMemcpyAsync(hx, x, nHx * sizeof(float), hipMemcpyDeviceToDevice, stream);
    rope_table_kernel<<<256, 256, 0, stream>>>(cosT, sinT);

    for (int layer = 0; layer < NL; ++layer) {
        wcast_t_kernel<<<dim3(1536 / 32, 512 / 32), 256, 0, stream>>>(
            wqkv + (size_t)layer * 512 * 1536, wqkvT + (size_t)layer * 1536 * 512, 512, 1536);
        wcast_t_kernel<<<dim3(512 / 32, 512 / 32), 256, 0, stream>>>(
            wout + (size_t)layer * 512 * 512, woutT + (size_t)layer * 512 * 512, 512, 512);
        wcast_t_kernel<<<dim3(2048 / 32, 512 / 32), 256, 0, stream>>>(
            wup + (size_t)layer * 512 * 2048, wupT + (size_t)layer * 2048 * 512, 512, 2048);
        wcast_t_kernel<<<dim3(512 / 32, 1024 / 32), 256, 0, stream>>>(
            wdown + (size_t)layer * 1024 * 512, wdownT + (size_t)layer * 512 * 1024, 1024, 512);
    }

    for (int layer = 0; layer < NL; ++layer) {
        const float* wn_a = wn_attn + (size_t)layer * DD * DD;
        const float* qs   = qk_scale + layer * HH;
        const float* wn_f = wn_ff + (size_t)layer * DD * DD;

        cond_gemm_kernel<<<4, 256, 0, stream>>>(cond, wn_a, s_attn);
        rmsnorm_bf16_kernel<<<TOK, 256, 0, stream>>>(hx, s_attn, y_bf);
        gemm_bf16_kernel<<<dim3(1536 / 128, TOK / 128), 256, 0, stream>>>(
            y_bf, wqkvT + (size_t)layer * 1536 * 512, nullptr, qkv, TOK, 1536, 512);
        qknorm_rope_kernel<<<TOK * HH / 4, 256, 0, stream>>>(qkv, qs, cosT, sinT, qh_bf, kh_bf);
        vtrans_kernel<<<NB * HH * (LL / 64), 256, 0, stream>>>(qkv, vt_bf);
        flash_mfma_kernel<<<NB * HH * (LL / 128), 256, 0, stream>>>(qh_bf, kh_bf, vt_bf, oh_bf);
        gemm_bf16_kernel<<<dim3(512 / 128, TOK / 128), 256, 0, stream>>>(
            oh_bf, woutT + (size_t)layer * 512 * 512, hx, hx, TOK, 512, 512);

        cond_gemm_kernel<<<4, 256, 0, stream>>>(cond, wn_f, s_ff);
        rmsnorm_bf16_kernel<<<TOK, 256, 0, stream>>>(hx, s_ff, y_bf);
        gemm_bf16_kernel<<<dim3(2048 / 128, TOK / 128), 256, 0, stream>>>(
            y_bf, wupT + (size_t)layer * 2048 * 512, nullptr, u, TOK, 2048, 512);
        geglu_kernel<<<TOK * DFF / 256, 256, 0, stream>>>(u, g_bf);
        gemm_bf16_kernel<<<dim3(512 / 128, TOK / 128), 256, 0, stream>>>(
            g_bf, wdownT + (size_t)layer * 512 * 1024, hx, hx, TOK, 512, 1024);
    }
    rmsnorm_f32_kernel<<<TOK, 256, 0, stream>>>(hx, out_scale, out);
}

// Round 7
// 1025.386 us; speedup vs baseline: 3.9764x; 1.4690x over previous
//
#include <hip/hip_runtime.h>
#include <hip/hip_bf16.h>

#define NB 2
#define LL 2048
#define DD 512
#define HH 8
#define EE 64
#define DFF 1024
#define NL 4
#define EPS_F 1e-6f

typedef __bf16 bf16x8 __attribute__((ext_vector_type(8)));
typedef float f32x4 __attribute__((ext_vector_type(4)));

// round-to-nearest-even f32 -> bf16 bits
__device__ __forceinline__ unsigned short f2bf(float f) {
    unsigned int u = __float_as_uint(f);
    unsigned int r = (u + 0x7FFFu + ((u >> 16) & 1u)) >> 16;
    return (unsigned short)r;
}

// ---------------------------------------------------------------------------
// rope table
// ---------------------------------------------------------------------------
__global__ void rope_table_kernel(float* __restrict__ cosT, float* __restrict__ sinT) {
    int idx = blockIdx.x * 256 + threadIdx.x;
    if (idx >= LL * 32) return;
    int l = idx >> 5, i = idx & 31;
    float inv = powf(10000.f, -(float)i * (1.f / 32.f));
    float ang = (float)l * inv;
    cosT[idx] = cosf(ang);
    sinT[idx] = sinf(ang);
}

// ---------------------------------------------------------------------------
// weight cast + transpose: W[K,N] f32 -> WT[N,K] bf16 bits. 32x32 LDS tile.
// ---------------------------------------------------------------------------
__global__ __launch_bounds__(256) void wcast_t_kernel(const float* __restrict__ W,
                                                      unsigned short* __restrict__ WT,
                                                      int K, int N) {
    __shared__ float tile[32][33];
    int n0 = blockIdx.x * 32, k0 = blockIdx.y * 32;
    int r = threadIdx.x >> 5, c = threadIdx.x & 31;
#pragma unroll
    for (int i = 0; i < 4; ++i)
        tile[r + 8 * i][c] = W[(size_t)(k0 + r + 8 * i) * N + n0 + c];
    __syncthreads();
#pragma unroll
    for (int i = 0; i < 4; ++i)
        WT[(size_t)(n0 + r + 8 * i) * K + k0 + c] = f2bf(tile[c][r + 8 * i]);
}

// ---------------------------------------------------------------------------
// all cond scales in ONE dispatch: s_all[(layer*2+which)*NB*DD + b*DD + d]
//  = 1 + cond[b,:] @ W[:,d],  W = (which ? wn_ff : wn_attn)[layer]
// 128 blocks: bid -> (d0, b, which, layer); 4-way k-split + LDS reduce.
// ---------------------------------------------------------------------------
__global__ __launch_bounds__(256) void cond_all_kernel(const float* __restrict__ cond,
                                                       const float* __restrict__ wn_attn,
                                                       const float* __restrict__ wn_ff,
                                                       float* __restrict__ s_all) {
    int bid = blockIdx.x;                 // 128 = NL*2*NB*8
    int d0 = (bid & 7) * 64;
    int b = (bid >> 3) & 1;
    int which = (bid >> 4) & 1;
    int layer = bid >> 5;
    const float* W = (which ? wn_ff : wn_attn) + (size_t)layer * DD * DD;
    int t = threadIdx.x;
    int d = d0 + (t & 63), kq = t >> 6;
    const float* c = cond + b * DD + kq * 128;
    const float* Wp = W + (size_t)(kq * 128) * DD + d;
    float s = 0.f;
#pragma unroll 8
    for (int j = 0; j < 128; ++j) s = fmaf(c[j], Wp[(size_t)j * DD], s);
    __shared__ float red[4][64];
    red[kq][t & 63] = s;
    __syncthreads();
    if (t < 64) {
        float tot = 1.f + red[0][t] + red[1][t] + red[2][t] + red[3][t];
        s_all[((size_t)(layer * 2 + which) * NB + b) * DD + d0 + t] = tot;
    }
}

// ---------------------------------------------------------------------------
// RMSNorm over D=512, scale (B,D), bf16 output
// ---------------------------------------------------------------------------
__global__ __launch_bounds__(256) void rmsnorm_bf16_kernel(const float* __restrict__ x,
                                                           const float* __restrict__ scale,
                                                           unsigned short* __restrict__ y) {
    int row = blockIdx.x;
    int b = row >> 11;
    int t = threadIdx.x;
    float2 v = ((const float2*)(x + (size_t)row * DD))[t];
    float ss = v.x * v.x + v.y * v.y;
#pragma unroll
    for (int o = 32; o > 0; o >>= 1) ss += __shfl_xor(ss, o);
    __shared__ float red[4];
    if ((t & 63) == 0) red[t >> 6] = ss;
    __syncthreads();
    float tot = red[0] + red[1] + red[2] + red[3];
    float inv = rsqrtf(tot * (1.f / DD) + EPS_F);
    float2 s2 = ((const float2*)(scale + b * DD))[t];
    unsigned int lo = f2bf(v.x * s2.x * inv);
    unsigned int hi = f2bf(v.y * s2.y * inv);
    ((unsigned int*)(y + (size_t)row * DD))[t] = lo | (hi << 16);
}

// RMSNorm, scale (D,), fp32 output (final)
__global__ __launch_bounds__(256) void rmsnorm_f32_kernel(const float* __restrict__ x,
                                                          const float* __restrict__ scale,
                                                          float* __restrict__ y) {
    int row = blockIdx.x;
    int t = threadIdx.x;
    float2 v = ((const float2*)(x + (size_t)row * DD))[t];
    float ss = v.x * v.x + v.y * v.y;
#pragma unroll
    for (int o = 32; o > 0; o >>= 1) ss += __shfl_xor(ss, o);
    __shared__ float red[4];
    if ((t & 63) == 0) red[t >> 6] = ss;
    __syncthreads();
    float tot = red[0] + red[1] + red[2] + red[3];
    float inv = rsqrtf(tot * (1.f / DD) + EPS_F);
    float2 s2 = ((const float2*)scale)[t];
    float2 o2;
    o2.x = v.x * s2.x * inv;
    o2.y = v.y * s2.y * inv;
    ((float2*)(y + (size_t)row * DD))[t] = o2;
}

// ---------------------------------------------------------------------------
// bf16 MFMA GEMM: C[M,N] = (R?R:0) + A[M,K] @ BT[N,K]^T
// ---------------------------------------------------------------------------
#define LDP 40
__global__ __launch_bounds__(256) void gemm_bf16_kernel(const unsigned short* __restrict__ A,
                                                        const unsigned short* __restrict__ BT,
                                                        const float* __restrict__ R,
                                                        float* __restrict__ C,
                                                        int M, int N, int K) {
    __shared__ unsigned short As[128 * LDP];
    __shared__ unsigned short Bs[128 * LDP];
    int tid = threadIdx.x;
    int n0 = blockIdx.x * 128, m0 = blockIdx.y * 128;
    int w = tid >> 6, l = tid & 63;
    int wr = w >> 1, wc = w & 1;
    int kf = 8 * (l >> 4);
    int rf = l & 15;

    f32x4 acc[4][4] = {};

    for (int k0 = 0; k0 < K; k0 += 32) {
#pragma unroll
        for (int u2 = 0; u2 < 2; ++u2) {
            int c = tid * 2 + u2;
            int row = c >> 2, ch = c & 3;
            uint4 av = *(const uint4*)(A + (size_t)(m0 + row) * K + k0 + ch * 8);
            *(uint4*)(&As[row * LDP + ch * 8]) = av;
            uint4 bv = *(const uint4*)(BT + (size_t)(n0 + row) * K + k0 + ch * 8);
            *(uint4*)(&Bs[row * LDP + ch * 8]) = bv;
        }
        __syncthreads();

        bf16x8 a[4], b[4];
#pragma unroll
        for (int i = 0; i < 4; ++i)
            a[i] = *(const bf16x8*)(&As[(wr * 64 + i * 16 + rf) * LDP + kf]);
#pragma unroll
        for (int j = 0; j < 4; ++j)
            b[j] = *(const bf16x8*)(&Bs[(wc * 64 + j * 16 + rf) * LDP + kf]);
#pragma unroll
        for (int i = 0; i < 4; ++i)
#pragma unroll
            for (int j = 0; j < 4; ++j)
                acc[i][j] = __builtin_amdgcn_mfma_f32_16x16x32_bf16(a[i], b[j], acc[i][j], 0, 0, 0);
        __syncthreads();
    }

    int rl = l >> 4, cl = l & 15;
#pragma unroll
    for (int i = 0; i < 4; ++i)
#pragma unroll
        for (int j = 0; j < 4; ++j)
#pragma unroll
            for (int r = 0; r < 4; ++r) {
                int row = m0 + wr * 64 + i * 16 + rl * 4 + r;
                int col = n0 + wc * 64 + j * 16 + cl;
                size_t off = (size_t)row * N + col;
                float v = acc[i][j][r];
                if (R) v += R[off];
                C[off] = v;
            }
}

// ---------------------------------------------------------------------------
// per-head RMSNorm + rope for q,k; bf16 out. 1/sqrt(8) folded into q and k.
// ---------------------------------------------------------------------------
__global__ __launch_bounds__(256) void qknorm_rope_kernel(const float* __restrict__ qkv,
                                                          const float* __restrict__ qs,
                                                          const float* __restrict__ cosT,
                                                          const float* __restrict__ sinT,
                                                          unsigned short* __restrict__ qh,
                                                          unsigned short* __restrict__ kh) {
    int w = blockIdx.x * 4 + (threadIdx.x >> 6);   // (b*L + l)*H + h
    int e = threadIdx.x & 63;
    int h = w & 7;
    int l = (w >> 3) & (LL - 1);
    int b = w >> 14;
    size_t rb = ((size_t)(b * LL + l)) * (3 * DD) + h * EE + e;
    float q = qkv[rb];
    float k = qkv[rb + DD];
    float sq = q * q, sk = k * k;
#pragma unroll
    for (int o = 1; o < 64; o <<= 1) {
        sq += __shfl_xor(sq, o);
        sk += __shfl_xor(sk, o);
    }
    float hsc = expf(0.5f * fminf(qs[h], 4.60517019f) - 1.03972077f) * 0.35355339059f;
    float qn = q * hsc * rsqrtf(sq * (1.f / EE) + EPS_F);
    float kn = k * hsc * rsqrtf(sk * (1.f / EE) + EPS_F);
    float qp = __shfl_xor(qn, 32);
    float kp = __shfl_xor(kn, 32);
    int i = e & 31;
    float c = cosT[l * 32 + i], s = sinT[l * 32 + i];
    float qo = (e < 32) ? (qn * c - qp * s) : (qp * s + qn * c);
    float ko = (e < 32) ? (kn * c - kp * s) : (kp * s + kn * c);
    size_t ob = ((size_t)((b * HH + h) * LL + l)) * EE + e;
    qh[ob] = f2bf(qo);
    kh[ob] = f2bf(ko);
}

// ---------------------------------------------------------------------------
// V transpose: qkv v-slice f32 [l][e] -> vt bf16 [bh*64+e][l]. 64x64 tiles.
// ---------------------------------------------------------------------------
__global__ __launch_bounds__(256) void vtrans_kernel(const float* __restrict__ qkv,
                                                     unsigned short* __restrict__ vt) {
    __shared__ float tile[64][65];
    int bid = blockIdx.x;            // 512 = 16 bh * 32 ltiles
    int lt = bid & 31, bh = bid >> 5;
    int b = bh >> 3, h = bh & 7;
    int l0 = lt * 64;
    int t = threadIdx.x;
#pragma unroll
    for (int i = 0; i < 4; ++i) {
        int c = t + i * 256;
        int row = c >> 4, q4 = c & 15;
        float4 v4 = *(const float4*)(qkv + ((size_t)(b * LL + l0 + row)) * (3 * DD) + 2 * DD + h * EE + q4 * 4);
        tile[row][q4 * 4 + 0] = v4.x;
        tile[row][q4 * 4 + 1] = v4.y;
        tile[row][q4 * 4 + 2] = v4.z;
        tile[row][q4 * 4 + 3] = v4.w;
    }
    __syncthreads();
    int e = t >> 2, lc = t & 3;
    unsigned int* dst = (unsigned int*)(vt + ((size_t)(bh * EE + e)) * LL + l0 + lc * 16);
#pragma unroll
    for (int j2 = 0; j2 < 8; ++j2) {
        unsigned int lo = f2bf(tile[lc * 16 + 2 * j2][e]);
        unsigned int hi = f2bf(tile[lc * 16 + 2 * j2 + 1][e]);
        dst[j2] = lo | (hi << 16);
    }
}

// ---------------------------------------------------------------------------
// MFMA flash attention v2. Block = 256 thr = 4 waves; wave owns 16 q-rows.
// QBLK=64 -> grid 512 blocks (2 blocks/CU, 8 waves/CU).
// ---------------------------------------------------------------------------
#define KVB 64
__global__ __launch_bounds__(256) void flash_mfma_kernel(const unsigned short* __restrict__ qh,
                                                         const unsigned short* __restrict__ kh,
                                                         const unsigned short* __restrict__ vt,
                                                         unsigned short* __restrict__ oh) {
    __shared__ unsigned short K_lds[64 * 72];
    __shared__ unsigned short VT_lds[64 * 72];
    __shared__ unsigned short P_lds[4][16 * 72];
    int bid = blockIdx.x;            // 512
    int qb = bid & 31, h = (bid >> 5) & 7, b = bid >> 8;
    int bh = b * HH + h;
    int tid = threadIdx.x, w = tid >> 6, l = tid & 63;
    int lo = l & 15, hi4 = l >> 4;
    int q0 = qb * 64 + w * 16;

    const unsigned short* qbase = qh + ((size_t)bh * LL) * EE;
    bf16x8 qa[2];
#pragma unroll
    for (int s = 0; s < 2; ++s)
        qa[s] = *(const bf16x8*)(qbase + (size_t)(q0 + lo) * EE + s * 32 + 8 * hi4);

    f32x4 oacc[4] = {};
    float mrow[4], lrow[4];
#pragma unroll
    for (int r = 0; r < 4; ++r) { mrow[r] = -3.0e38f; lrow[r] = 0.f; }

    for (int kt = 0; kt < LL / KVB; ++kt) {
        int kv0 = kt * KVB;
#pragma unroll
        for (int u = 0; u < 4; ++u) {
            int c = tid + u * 256;           // 0..1023
            int arr = c >> 9, cc = c & 511;
            int row = cc >> 3, ch = cc & 7;
            if (arr == 0)
                *(uint4*)&K_lds[row * 72 + ch * 8] =
                    *(const uint4*)(kh + ((size_t)bh * LL + kv0 + row) * EE + ch * 8);
            else
                *(uint4*)&VT_lds[row * 72 + ch * 8] =
                    *(const uint4*)(vt + ((size_t)bh * EE + row) * LL + kv0 + ch * 8);
        }
        __syncthreads();

        // S = Q K^T (scale pre-folded)
        f32x4 S[4] = {};
        __builtin_amdgcn_s_setprio(1);
#pragma unroll
        for (int nf = 0; nf < 4; ++nf) {
#pragma unroll
            for (int s = 0; s < 2; ++s) {
                bf16x8 kb = *(const bf16x8*)&K_lds[(nf * 16 + lo) * 72 + s * 32 + 8 * hi4];
                S[nf] = __builtin_amdgcn_mfma_f32_16x16x32_bf16(qa[s], kb, S[nf], 0, 0, 0);
            }
        }
        __builtin_amdgcn_s_setprio(0);

        // online softmax; 4 rows per lane group (row = hi4*4 + r)
#pragma unroll
        for (int r = 0; r < 4; ++r) {
            float t0 = fmaxf(fmaxf(S[0][r], S[1][r]), fmaxf(S[2][r], S[3][r]));
#pragma unroll
            for (int d = 1; d < 16; d <<= 1) t0 = fmaxf(t0, __shfl_xor(t0, d));
            float mn = fmaxf(mrow[r], t0);
            float corr = expf(mrow[r] - mn);
            mrow[r] = mn;
            lrow[r] *= corr;
            float rs = 0.f;
#pragma unroll
            for (int nf = 0; nf < 4; ++nf) {
                float p = expf(S[nf][r] - mn);
                rs += p;
                P_lds[w][(hi4 * 4 + r) * 72 + nf * 16 + lo] = f2bf(p);
            }
#pragma unroll
            for (int d = 1; d < 16; d <<= 1) rs += __shfl_xor(rs, d);
            lrow[r] += rs;
#pragma unroll
            for (int nf = 0; nf < 4; ++nf) oacc[nf][r] *= corr;
        }

        // O += P V
        __builtin_amdgcn_s_setprio(1);
#pragma unroll
        for (int s = 0; s < 2; ++s) {
            bf16x8 pa = *(const bf16x8*)&P_lds[w][lo * 72 + s * 32 + 8 * hi4];
#pragma unroll
            for (int nf = 0; nf < 4; ++nf) {
                bf16x8 vb = *(const bf16x8*)&VT_lds[(nf * 16 + lo) * 72 + s * 32 + 8 * hi4];
                oacc[nf] = __builtin_amdgcn_mfma_f32_16x16x32_bf16(pa, vb, oacc[nf], 0, 0, 0);
            }
        }
        __builtin_amdgcn_s_setprio(0);
        __syncthreads();
    }

#pragma unroll
    for (int r = 0; r < 4; ++r) {
        float inv = 1.f / lrow[r];
        int row = q0 + hi4 * 4 + r;
        unsigned short* op = oh + ((size_t)(b * LL + row)) * DD + h * EE;
#pragma unroll
        for (int nf = 0; nf < 4; ++nf)
            op[nf * 16 + lo] = f2bf(oacc[nf][r] * inv);
    }
}

// ---------------------------------------------------------------------------
// geglu: g = bf16( a * gelu_exact(b) )
// ---------------------------------------------------------------------------
__global__ void geglu_kernel(const float* __restrict__ u, unsigned short* __restrict__ g) {
    int idx = blockIdx.x * 256 + threadIdx.x;
    int r = idx >> 10, j = idx & 1023;
    float a = u[(size_t)r * (2 * DFF) + j];
    float x = u[(size_t)r * (2 * DFF) + DFF + j];
    float ge = 0.5f * x * (1.f + erff(x * 0.70710678f));
    g[idx] = f2bf(a * ge);
}

// ---------------------------------------------------------------------------
extern "C" void kernel_launch(void* const* d_in, const int* in_sizes, int n_in,
                              void* d_out, int out_size, void* d_ws, size_t ws_size,
                              hipStream_t stream) {
    const float* x        = (const float*)d_in[0];
    const float* cond     = (const float*)d_in[1];
    // d_in[2] attn_mask: bias varies only with query index -> softmax-invariant -> unused
    const float* wn_attn  = (const float*)d_in[3];
    const float* wqkv     = (const float*)d_in[4];
    const float* qk_scale = (const float*)d_in[5];
    const float* wout     = (const float*)d_in[6];
    const float* wn_ff    = (const float*)d_in[7];
    const float* wup      = (const float*)d_in[8];
    const float* wdown    = (const float*)d_in[9];
    const float* out_scale= (const float*)d_in[10];
    float* out = (float*)d_out;

    const int TOK = NB * LL;                 // 4096
    const size_t nHx = (size_t)TOK * DD;     // 2,097,152
    const size_t M = 1024 * 1024;

    float* ws = (float*)d_ws;
    float* hx  = ws;                                   // [0, 2M) f32
    unsigned short* y_bf = (unsigned short*)(ws + 2 * M);      // [2M,3M) 2M ushort
    float* qkv = ws + 3 * M;                           // [3M, 9M) f32
    float* u   = ws + 3 * M;                           // [3M, 11M) f32 (aliases qkv)
    unsigned short* qh_bf = (unsigned short*)(ws + 11 * M);    // [11M,12M)
    unsigned short* g_bf  = (unsigned short*)(ws + 11 * M);    // [11M,13M) (qh/kh dead by geglu)
    unsigned short* kh_bf = (unsigned short*)(ws + 12 * M);    // [12M,13M)
    unsigned short* vt_bf = (unsigned short*)(ws + 13 * M);    // [13M,14M)
    unsigned short* oh_bf = (unsigned short*)(ws + 14 * M);    // [14M,15M)
    unsigned short* wt = (unsigned short*)(ws + 15 * M);       // [15M,20M)
    unsigned short* wqkvT  = wt;
    unsigned short* woutT  = wt + 3145728;
    unsigned short* wupT   = wt + 4194304;
    unsigned short* wdownT = wt + 8388608;
    float* smal  = ws + 20 * M;
    float* s_all = smal;                      // NL*2*NB*DD = 8192
    float* cosT  = smal + 8192;
    float* sinT  = cosT + 65536;

    hipMemcpyAsync(hx, x, nHx * sizeof(float), hipMemcpyDeviceToDevice, stream);
    rope_table_kernel<<<256, 256, 0, stream>>>(cosT, sinT);
    cond_all_kernel<<<128, 256, 0, stream>>>(cond, wn_attn, wn_ff, s_all);

    for (int layer = 0; layer < NL; ++layer) {
        wcast_t_kernel<<<dim3(1536 / 32, 512 / 32), 256, 0, stream>>>(
            wqkv + (size_t)layer * 512 * 1536, wqkvT + (size_t)layer * 1536 * 512, 512, 1536);
        wcast_t_kernel<<<dim3(512 / 32, 512 / 32), 256, 0, stream>>>(
            wout + (size_t)layer * 512 * 512, woutT + (size_t)layer * 512 * 512, 512, 512);
        wcast_t_kernel<<<dim3(2048 / 32, 512 / 32), 256, 0, stream>>>(
            wup + (size_t)layer * 512 * 2048, wupT + (size_t)layer * 2048 * 512, 512, 2048);
        wcast_t_kernel<<<dim3(512 / 32, 1024 / 32), 256, 0, stream>>>(
            wdown + (size_t)layer * 1024 * 512, wdownT + (size_t)layer * 512 * 1024, 1024, 512);
    }

    for (int layer = 0; layer < NL; ++layer) {
        const float* qs = qk_scale + layer * HH;

        rmsnorm_bf16_kernel<<<TOK, 256, 0, stream>>>(hx, s_all + (size_t)(layer * 2 + 0) * NB * DD, y_bf);
        gemm_bf16_kernel<<<dim3(1536 / 128, TOK / 128), 256, 0, stream>>>(
            y_bf, wqkvT + (size_t)layer * 1536 * 512, nullptr, qkv, TOK, 1536, 512);
        qknorm_rope_kernel<<<TOK * HH / 4, 256, 0, stream>>>(qkv, qs, cosT, sinT, qh_bf, kh_bf);
        vtrans_kernel<<<NB * HH * (LL / 64), 256, 0, stream>>>(qkv, vt_bf);
        flash_mfma_kernel<<<NB * HH * (LL / 64), 256, 0, stream>>>(qh_bf, kh_bf, vt_bf, oh_bf);
        gemm_bf16_kernel<<<dim3(512 / 128, TOK / 128), 256, 0, stream>>>(
            oh_bf, woutT + (size_t)layer * 512 * 512, hx, hx, TOK, 512, 512);

        rmsnorm_bf16_kernel<<<TOK, 256, 0, stream>>>(hx, s_all + (size_t)(layer * 2 + 1) * NB * DD, y_bf);
        gemm_bf16_kernel<<<dim3(2048 / 128, TOK / 128), 256, 0, stream>>>(
            y_bf, wupT + (size_t)layer * 2048 * 512, nullptr, u, TOK, 2048, 512);
        geglu_kernel<<<TOK * DFF / 256, 256, 0, stream>>>(u, g_bf);
        gemm_bf16_kernel<<<dim3(512 / 128, TOK / 128), 256, 0, stream>>>(
            g_bf, wdownT + (size_t)layer * 512 * 1024, hx, hx, TOK, 512, 1024);
    }
    rmsnorm_f32_kernel<<<TOK, 256, 0, stream>>>(hx, out_scale, out);
}

// Round 9
// 850.796 us; speedup vs baseline: 4.7923x; 1.2052x over previous
//
#include <hip/hip_runtime.h>
#include <hip/hip_bf16.h>

#define NB 2
#define LL 2048
#define DD 512
#define HH 8
#define EE 64
#define DFF 1024
#define NL 4
#define EPS_F 1e-6f

typedef __bf16 bf16x8 __attribute__((ext_vector_type(8)));
typedef float f32x4 __attribute__((ext_vector_type(4)));

// round-to-nearest-even f32 -> bf16 bits
__device__ __forceinline__ unsigned short f2bf(float f) {
    unsigned int u = __float_as_uint(f);
    unsigned int r = (u + 0x7FFFu + ((u >> 16) & 1u)) >> 16;
    return (unsigned short)r;
}

// ---------------------------------------------------------------------------
// rope table
// ---------------------------------------------------------------------------
__global__ void rope_table_kernel(float* __restrict__ cosT, float* __restrict__ sinT) {
    int idx = blockIdx.x * 256 + threadIdx.x;
    if (idx >= LL * 32) return;
    int l = idx >> 5, i = idx & 31;
    float inv = powf(10000.f, -(float)i * (1.f / 32.f));
    float ang = (float)l * inv;
    cosT[idx] = cosf(ang);
    sinT[idx] = sinf(ang);
}

// ---------------------------------------------------------------------------
// ALL weight cast+transpose in one dispatch. 10240 blocks of 32x32 tiles.
// ---------------------------------------------------------------------------
__global__ __launch_bounds__(256) void wcast_all_kernel(const float* __restrict__ wqkv,
                                                        const float* __restrict__ wout,
                                                        const float* __restrict__ wup,
                                                        const float* __restrict__ wdown,
                                                        unsigned short* __restrict__ wt) {
    int bid = blockIdx.x;                 // 10240 = 4 layers * 2560 tiles
    int layer = bid / 2560, rem = bid % 2560;
    const float* W; unsigned short* WT; int K, N, t;
    if (rem < 768)       { W = wqkv  + (size_t)layer * 786432;  WT = wt + (size_t)layer * 786432;            K = 512;  N = 1536; t = rem; }
    else if (rem < 1024) { W = wout  + (size_t)layer * 262144;  WT = wt + 3145728 + (size_t)layer * 262144;  K = 512;  N = 512;  t = rem - 768; }
    else if (rem < 2048) { W = wup   + (size_t)layer * 1048576; WT = wt + 4194304 + (size_t)layer * 1048576; K = 512;  N = 2048; t = rem - 1024; }
    else                 { W = wdown + (size_t)layer * 524288;  WT = wt + 8388608 + (size_t)layer * 524288;  K = 1024; N = 512;  t = rem - 2048; }
    int tn = N / 32;
    int n0 = (t % tn) * 32, k0 = (t / tn) * 32;
    __shared__ float tile[32][33];
    int r = threadIdx.x >> 5, c = threadIdx.x & 31;
#pragma unroll
    for (int i = 0; i < 4; ++i)
        tile[r + 8 * i][c] = W[(size_t)(k0 + r + 8 * i) * N + n0 + c];
    __syncthreads();
#pragma unroll
    for (int i = 0; i < 4; ++i)
        WT[(size_t)(n0 + r + 8 * i) * K + k0 + c] = f2bf(tile[c][r + 8 * i]);
}

// ---------------------------------------------------------------------------
// all cond scales in ONE dispatch
// ---------------------------------------------------------------------------
__global__ __launch_bounds__(256) void cond_all_kernel(const float* __restrict__ cond,
                                                       const float* __restrict__ wn_attn,
                                                       const float* __restrict__ wn_ff,
                                                       float* __restrict__ s_all) {
    int bid = blockIdx.x;                 // 128
    int d0 = (bid & 7) * 64;
    int b = (bid >> 3) & 1;
    int which = (bid >> 4) & 1;
    int layer = bid >> 5;
    const float* W = (which ? wn_ff : wn_attn) + (size_t)layer * DD * DD;
    int t = threadIdx.x;
    int d = d0 + (t & 63), kq = t >> 6;
    const float* c = cond + b * DD + kq * 128;
    const float* Wp = W + (size_t)(kq * 128) * DD + d;
    float s = 0.f;
#pragma unroll 8
    for (int j = 0; j < 128; ++j) s = fmaf(c[j], Wp[(size_t)j * DD], s);
    __shared__ float red[4][64];
    red[kq][t & 63] = s;
    __syncthreads();
    if (t < 64) {
        float tot = 1.f + red[0][t] + red[1][t] + red[2][t] + red[3][t];
        s_all[((size_t)(layer * 2 + which) * NB + b) * DD + d0 + t] = tot;
    }
}

// ---------------------------------------------------------------------------
// RMSNorm over D=512, scale (B,D), bf16 output
// ---------------------------------------------------------------------------
__global__ __launch_bounds__(256) void rmsnorm_bf16_kernel(const float* __restrict__ x,
                                                           const float* __restrict__ scale,
                                                           unsigned short* __restrict__ y) {
    int row = blockIdx.x;
    int b = row >> 11;
    int t = threadIdx.x;
    float2 v = ((const float2*)(x + (size_t)row * DD))[t];
    float ss = v.x * v.x + v.y * v.y;
#pragma unroll
    for (int o = 32; o > 0; o >>= 1) ss += __shfl_xor(ss, o);
    __shared__ float red[4];
    if ((t & 63) == 0) red[t >> 6] = ss;
    __syncthreads();
    float tot = red[0] + red[1] + red[2] + red[3];
    float inv = rsqrtf(tot * (1.f / DD) + EPS_F);
    float2 s2 = ((const float2*)(scale + b * DD))[t];
    unsigned int lo = f2bf(v.x * s2.x * inv);
    unsigned int hi = f2bf(v.y * s2.y * inv);
    ((unsigned int*)(y + (size_t)row * DD))[t] = lo | (hi << 16);
}

// RMSNorm, scale (D,), fp32 output (final)
__global__ __launch_bounds__(256) void rmsnorm_f32_kernel(const float* __restrict__ x,
                                                          const float* __restrict__ scale,
                                                          float* __restrict__ y) {
    int row = blockIdx.x;
    int t = threadIdx.x;
    float2 v = ((const float2*)(x + (size_t)row * DD))[t];
    float ss = v.x * v.x + v.y * v.y;
#pragma unroll
    for (int o = 32; o > 0; o >>= 1) ss += __shfl_xor(ss, o);
    __shared__ float red[4];
    if ((t & 63) == 0) red[t >> 6] = ss;
    __syncthreads();
    float tot = red[0] + red[1] + red[2] + red[3];
    float inv = rsqrtf(tot * (1.f / DD) + EPS_F);
    float2 s2 = ((const float2*)scale)[t];
    float2 o2;
    o2.x = v.x * s2.x * inv;
    o2.y = v.y * s2.y * inv;
    ((float2*)(y + (size_t)row * DD))[t] = o2;
}

// ---------------------------------------------------------------------------
// bf16 MFMA GEMM: C[M,N] = (R?R:0) + A[M,K] @ BT[N,K]^T
// ---------------------------------------------------------------------------
#define LDP 40
__global__ __launch_bounds__(256) void gemm_bf16_kernel(const unsigned short* __restrict__ A,
                                                        const unsigned short* __restrict__ BT,
                                                        const float* __restrict__ R,
                                                        float* __restrict__ C,
                                                        int M, int N, int K) {
    __shared__ unsigned short As[128 * LDP];
    __shared__ unsigned short Bs[128 * LDP];
    int tid = threadIdx.x;
    int n0 = blockIdx.x * 128, m0 = blockIdx.y * 128;
    int w = tid >> 6, l = tid & 63;
    int wr = w >> 1, wc = w & 1;
    int kf = 8 * (l >> 4);
    int rf = l & 15;

    f32x4 acc[4][4] = {};

    for (int k0 = 0; k0 < K; k0 += 32) {
#pragma unroll
        for (int u2 = 0; u2 < 2; ++u2) {
            int c = tid * 2 + u2;
            int row = c >> 2, ch = c & 3;
            uint4 av = *(const uint4*)(A + (size_t)(m0 + row) * K + k0 + ch * 8);
            *(uint4*)(&As[row * LDP + ch * 8]) = av;
            uint4 bv = *(const uint4*)(BT + (size_t)(n0 + row) * K + k0 + ch * 8);
            *(uint4*)(&Bs[row * LDP + ch * 8]) = bv;
        }
        __syncthreads();

        bf16x8 a[4], b[4];
#pragma unroll
        for (int i = 0; i < 4; ++i)
            a[i] = *(const bf16x8*)(&As[(wr * 64 + i * 16 + rf) * LDP + kf]);
#pragma unroll
        for (int j = 0; j < 4; ++j)
            b[j] = *(const bf16x8*)(&Bs[(wc * 64 + j * 16 + rf) * LDP + kf]);
#pragma unroll
        for (int i = 0; i < 4; ++i)
#pragma unroll
            for (int j = 0; j < 4; ++j)
                acc[i][j] = __builtin_amdgcn_mfma_f32_16x16x32_bf16(a[i], b[j], acc[i][j], 0, 0, 0);
        __syncthreads();
    }

    int rl = l >> 4, cl = l & 15;
#pragma unroll
    for (int i = 0; i < 4; ++i)
#pragma unroll
        for (int j = 0; j < 4; ++j)
#pragma unroll
            for (int r = 0; r < 4; ++r) {
                int row = m0 + wr * 64 + i * 16 + rl * 4 + r;
                int col = n0 + wc * 64 + j * 16 + cl;
                size_t off = (size_t)row * N + col;
                float v = acc[i][j][r];
                if (R) v += R[off];
                C[off] = v;
            }
}

// ---------------------------------------------------------------------------
// wup GEMM + fused geglu. Block computes a-cols [n0,n0+64) and b-cols
// [1024+n0, 1024+n0+64); epilogue: g = bf16(a * gelu_exact(b)).
// a-half exchanged through f32 LDS for exact precision. Grid (16, 32).
// ---------------------------------------------------------------------------
__global__ __launch_bounds__(256) void gemm_geglu_kernel(const unsigned short* __restrict__ A,
                                                         const unsigned short* __restrict__ BT,
                                                         unsigned short* __restrict__ G) {
    __shared__ unsigned short As[128 * LDP];
    __shared__ unsigned short Bs[128 * LDP];
    __shared__ float ep[128][65];
    int tid = threadIdx.x;
    int n0 = blockIdx.x * 64, m0 = blockIdx.y * 128;
    int w = tid >> 6, l = tid & 63;
    int wr = w >> 1, wc = w & 1;
    int kf = 8 * (l >> 4);
    int rf = l & 15;

    f32x4 acc[4][4] = {};

    for (int k0 = 0; k0 < DD; k0 += 32) {
#pragma unroll
        for (int u2 = 0; u2 < 2; ++u2) {
            int c = tid * 2 + u2;
            int row = c >> 2, ch = c & 3;
            uint4 av = *(const uint4*)(A + (size_t)(m0 + row) * DD + k0 + ch * 8);
            *(uint4*)(&As[row * LDP + ch * 8]) = av;
            int grow = (row < 64) ? (n0 + row) : (DFF + n0 + row - 64);
            uint4 bv = *(const uint4*)(BT + (size_t)grow * DD + k0 + ch * 8);
            *(uint4*)(&Bs[row * LDP + ch * 8]) = bv;
        }
        __syncthreads();

        bf16x8 a[4], b[4];
#pragma unroll
        for (int i = 0; i < 4; ++i)
            a[i] = *(const bf16x8*)(&As[(wr * 64 + i * 16 + rf) * LDP + kf]);
#pragma unroll
        for (int j = 0; j < 4; ++j)
            b[j] = *(const bf16x8*)(&Bs[(wc * 64 + j * 16 + rf) * LDP + kf]);
#pragma unroll
        for (int i = 0; i < 4; ++i)
#pragma unroll
            for (int j = 0; j < 4; ++j)
                acc[i][j] = __builtin_amdgcn_mfma_f32_16x16x32_bf16(a[i], b[j], acc[i][j], 0, 0, 0);
        __syncthreads();
    }

    int rl = l >> 4, cl = l & 15;
    if (wc == 0) {  // a-cols -> LDS
#pragma unroll
        for (int i = 0; i < 4; ++i)
#pragma unroll
            for (int j = 0; j < 4; ++j)
#pragma unroll
                for (int r = 0; r < 4; ++r)
                    ep[wr * 64 + i * 16 + rl * 4 + r][j * 16 + cl] = acc[i][j][r];
    }
    __syncthreads();
    if (wc == 1) {  // b-cols: g = a * gelu(b)
#pragma unroll
        for (int i = 0; i < 4; ++i)
#pragma unroll
            for (int j = 0; j < 4; ++j)
#pragma unroll
                for (int r = 0; r < 4; ++r) {
                    int row = wr * 64 + i * 16 + rl * 4 + r;
                    float bv = acc[i][j][r];
                    float av = ep[row][j * 16 + cl];
                    float ge = 0.5f * bv * (1.f + erff(bv * 0.70710678f));
                    G[(size_t)(m0 + row) * DFF + n0 + j * 16 + cl] = f2bf(av * ge);
                }
    }
}

// ---------------------------------------------------------------------------
// fused qknorm+rope (blocks 0..8191) and V transpose (blocks 8192..8703)
// ---------------------------------------------------------------------------
__global__ __launch_bounds__(256) void qkv_prep_kernel(const float* __restrict__ qkv,
                                                       const float* __restrict__ qs,
                                                       const float* __restrict__ cosT,
                                                       const float* __restrict__ sinT,
                                                       unsigned short* __restrict__ qh,
                                                       unsigned short* __restrict__ kh,
                                                       unsigned short* __restrict__ vt) {
    __shared__ float tile[64][65];
    int t = threadIdx.x;
    if (blockIdx.x < 8192) {
        int w = blockIdx.x * 4 + (t >> 6);   // (b*L + l)*H + h
        int e = t & 63;
        int h = w & 7;
        int l = (w >> 3) & (LL - 1);
        int b = w >> 14;
        size_t rb = ((size_t)(b * LL + l)) * (3 * DD) + h * EE + e;
        float q = qkv[rb];
        float k = qkv[rb + DD];
        float sq = q * q, sk = k * k;
#pragma unroll
        for (int o = 1; o < 64; o <<= 1) {
            sq += __shfl_xor(sq, o);
            sk += __shfl_xor(sk, o);
        }
        float hsc = expf(0.5f * fminf(qs[h], 4.60517019f) - 1.03972077f) * 0.35355339059f;
        float qn = q * hsc * rsqrtf(sq * (1.f / EE) + EPS_F);
        float kn = k * hsc * rsqrtf(sk * (1.f / EE) + EPS_F);
        float qp = __shfl_xor(qn, 32);
        float kp = __shfl_xor(kn, 32);
        int i = e & 31;
        float c = cosT[l * 32 + i], s = sinT[l * 32 + i];
        float qo = (e < 32) ? (qn * c - qp * s) : (qp * s + qn * c);
        float ko = (e < 32) ? (kn * c - kp * s) : (kp * s + kn * c);
        size_t ob = ((size_t)((b * HH + h) * LL + l)) * EE + e;
        qh[ob] = f2bf(qo);
        kh[ob] = f2bf(ko);
    } else {
        int bid = blockIdx.x - 8192;     // 512 = 16 bh * 32 ltiles
        int lt = bid & 31, bh = bid >> 5;
        int b = bh >> 3, h = bh & 7;
        int l0 = lt * 64;
#pragma unroll
        for (int i = 0; i < 4; ++i) {
            int c = t + i * 256;
            int row = c >> 4, q4 = c & 15;
            float4 v4 = *(const float4*)(qkv + ((size_t)(b * LL + l0 + row)) * (3 * DD) + 2 * DD + h * EE + q4 * 4);
            tile[row][q4 * 4 + 0] = v4.x;
            tile[row][q4 * 4 + 1] = v4.y;
            tile[row][q4 * 4 + 2] = v4.z;
            tile[row][q4 * 4 + 3] = v4.w;
        }
        __syncthreads();
        int e = t >> 2, lc = t & 3;
        unsigned int* dst = (unsigned int*)(vt + ((size_t)(bh * EE + e)) * LL + l0 + lc * 16);
#pragma unroll
        for (int j2 = 0; j2 < 8; ++j2) {
            unsigned int lo = f2bf(tile[lc * 16 + 2 * j2][e]);
            unsigned int hi = f2bf(tile[lc * 16 + 2 * j2 + 1][e]);
            dst[j2] = lo | (hi << 16);
        }
    }
}

// ---------------------------------------------------------------------------
// MFMA flash attention v3: NO max tracking (|S| <= 10 guaranteed by the
// rms-norm + hs clamp at qs=log10: ||q||=||k||<=3.16 -> Cauchy-Schwarz),
// P = exp(S) directly. Row sums via MFMA: VT_lds row 64 = ones; PV extra
// fragment col 64 = sum(P). 4 waves; wave owns 16 q-rows; grid 512 blocks.
// ---------------------------------------------------------------------------
#define KVB 64
__global__ __launch_bounds__(256) void flash_mfma_kernel(const unsigned short* __restrict__ qh,
                                                         const unsigned short* __restrict__ kh,
                                                         const unsigned short* __restrict__ vt,
                                                         unsigned short* __restrict__ oh) {
    __shared__ unsigned short K_lds[64 * 72];
    __shared__ unsigned short VT_lds[80 * 72];   // rows 64..79: ones row + zeros
    __shared__ unsigned short P_lds[4][16 * 72];
    int bid = blockIdx.x;            // 512
    int qb = bid & 31, h = (bid >> 5) & 7, b = bid >> 8;
    int bh = b * HH + h;
    int tid = threadIdx.x, w = tid >> 6, l = tid & 63;
    int lo = l & 15, hi4 = l >> 4;
    int q0 = qb * 64 + w * 16;

    // one-time: e=64 row of ones (bf16 1.0 = 0x3F80), rows 65..79 zero.
    for (int idx = tid; idx < 16 * 72; idx += 256) {
        int rr = idx / 72;
        VT_lds[(64 + rr) * 72 + (idx - rr * 72)] = (rr == 0) ? 0x3F80 : 0;
    }

    const unsigned short* qbase = qh + ((size_t)bh * LL) * EE;
    bf16x8 qa[2];
#pragma unroll
    for (int s = 0; s < 2; ++s)
        qa[s] = *(const bf16x8*)(qbase + (size_t)(q0 + lo) * EE + s * 32 + 8 * hi4);

    f32x4 oacc[4] = {};
    f32x4 osum = {};

    for (int kt = 0; kt < LL / KVB; ++kt) {
        int kv0 = kt * KVB;
#pragma unroll
        for (int u = 0; u < 4; ++u) {
            int c = tid + u * 256;           // 0..1023
            int arr = c >> 9, cc = c & 511;
            int row = cc >> 3, ch = cc & 7;
            if (arr == 0)
                *(uint4*)&K_lds[row * 72 + ch * 8] =
                    *(const uint4*)(kh + ((size_t)bh * LL + kv0 + row) * EE + ch * 8);
            else
                *(uint4*)&VT_lds[row * 72 + ch * 8] =
                    *(const uint4*)(vt + ((size_t)bh * EE + row) * LL + kv0 + ch * 8);
        }
        __syncthreads();

        // S = Q K^T (scale pre-folded)
        f32x4 S[4] = {};
        __builtin_amdgcn_s_setprio(1);
#pragma unroll
        for (int nf = 0; nf < 4; ++nf) {
#pragma unroll
            for (int s = 0; s < 2; ++s) {
                bf16x8 kb = *(const bf16x8*)&K_lds[(nf * 16 + lo) * 72 + s * 32 + 8 * hi4];
                S[nf] = __builtin_amdgcn_mfma_f32_16x16x32_bf16(qa[s], kb, S[nf], 0, 0, 0);
            }
        }
        __builtin_amdgcn_s_setprio(0);

        // P = exp(S) -- no max subtraction needed (S bounded), no sum tree
#pragma unroll
        for (int r = 0; r < 4; ++r)
#pragma unroll
            for (int nf = 0; nf < 4; ++nf)
                P_lds[w][(hi4 * 4 + r) * 72 + nf * 16 + lo] = f2bf(expf(S[nf][r]));

        // O += P V ; col 64 (ones row) accumulates row sums
        __builtin_amdgcn_s_setprio(1);
#pragma unroll
        for (int s = 0; s < 2; ++s) {
            bf16x8 pa = *(const bf16x8*)&P_lds[w][lo * 72 + s * 32 + 8 * hi4];
#pragma unroll
            for (int nf = 0; nf < 4; ++nf) {
                bf16x8 vb = *(const bf16x8*)&VT_lds[(nf * 16 + lo) * 72 + s * 32 + 8 * hi4];
                oacc[nf] = __builtin_amdgcn_mfma_f32_16x16x32_bf16(pa, vb, oacc[nf], 0, 0, 0);
            }
            bf16x8 vbE = *(const bf16x8*)&VT_lds[(64 + lo) * 72 + s * 32 + 8 * hi4];
            osum = __builtin_amdgcn_mfma_f32_16x16x32_bf16(pa, vbE, osum, 0, 0, 0);
        }
        __builtin_amdgcn_s_setprio(0);
        __syncthreads();
    }

#pragma unroll
    for (int r = 0; r < 4; ++r) {
        float lsum = __shfl(osum[r], (l & 48));   // value from lane lo==0 of group
        float inv = 1.f / lsum;
        int row = q0 + hi4 * 4 + r;
        unsigned short* op = oh + ((size_t)(b * LL + row)) * DD + h * EE;
#pragma unroll
        for (int nf = 0; nf < 4; ++nf)
            op[nf * 16 + lo] = f2bf(oacc[nf][r] * inv);
    }
}

// ---------------------------------------------------------------------------
extern "C" void kernel_launch(void* const* d_in, const int* in_sizes, int n_in,
                              void* d_out, int out_size, void* d_ws, size_t ws_size,
                              hipStream_t stream) {
    const float* x        = (const float*)d_in[0];
    const float* cond     = (const float*)d_in[1];
    // d_in[2] attn_mask: bias varies only with query index -> softmax-invariant -> unused
    const float* wn_attn  = (const float*)d_in[3];
    const float* wqkv     = (const float*)d_in[4];
    const float* qk_scale = (const float*)d_in[5];
    const float* wout     = (const float*)d_in[6];
    const float* wn_ff    = (const float*)d_in[7];
    const float* wup      = (const float*)d_in[8];
    const float* wdown    = (const float*)d_in[9];
    const float* out_scale= (const float*)d_in[10];
    float* out = (float*)d_out;

    const int TOK = NB * LL;                 // 4096
    const size_t nHx = (size_t)TOK * DD;     // 2,097,152
    const size_t M = 1024 * 1024;

    float* ws = (float*)d_ws;
    float* hx  = ws;                                   // [0, 2M) f32
    unsigned short* y_bf = (unsigned short*)(ws + 2 * M);      // [2M,3M)
    float* qkv = ws + 3 * M;                           // [3M, 9M) f32
    unsigned short* qh_bf = (unsigned short*)(ws + 11 * M);    // [11M,12M)
    unsigned short* g_bf  = (unsigned short*)(ws + 11 * M);    // [11M,13M) (qh/kh dead by geglu)
    unsigned short* kh_bf = (unsigned short*)(ws + 12 * M);    // [12M,13M)
    unsigned short* vt_bf = (unsigned short*)(ws + 13 * M);    // [13M,14M)
    unsigned short* oh_bf = (unsigned short*)(ws + 14 * M);    // [14M,15M)
    unsigned short* wt = (unsigned short*)(ws + 15 * M);       // [15M,20M)
    float* smal  = ws + 20 * M;
    float* s_all = smal;                      // NL*2*NB*DD = 8192
    float* cosT  = smal + 8192;
    float* sinT  = cosT + 65536;

    hipMemcpyAsync(hx, x, nHx * sizeof(float), hipMemcpyDeviceToDevice, stream);
    rope_table_kernel<<<256, 256, 0, stream>>>(cosT, sinT);
    cond_all_kernel<<<128, 256, 0, stream>>>(cond, wn_attn, wn_ff, s_all);
    wcast_all_kernel<<<10240, 256, 0, stream>>>(wqkv, wout, wup, wdown, wt);

    unsigned short* wqkvT  = wt;
    unsigned short* woutT  = wt + 3145728;
    unsigned short* wupT   = wt + 4194304;
    unsigned short* wdownT = wt + 8388608;

    for (int layer = 0; layer < NL; ++layer) {
        const float* qs = qk_scale + layer * HH;

        rmsnorm_bf16_kernel<<<TOK, 256, 0, stream>>>(hx, s_all + (size_t)(layer * 2 + 0) * NB * DD, y_bf);
        gemm_bf16_kernel<<<dim3(1536 / 128, TOK / 128), 256, 0, stream>>>(
            y_bf, wqkvT + (size_t)layer * 786432, nullptr, qkv, TOK, 1536, 512);
        qkv_prep_kernel<<<8704, 256, 0, stream>>>(qkv, qs, cosT, sinT, qh_bf, kh_bf, vt_bf);
        flash_mfma_kernel<<<NB * HH * (LL / 64), 256, 0, stream>>>(qh_bf, kh_bf, vt_bf, oh_bf);
        gemm_bf16_kernel<<<dim3(512 / 128, TOK / 128), 256, 0, stream>>>(
            oh_bf, woutT + (size_t)layer * 262144, hx, hx, TOK, 512, 512);

        rmsnorm_bf16_kernel<<<TOK, 256, 0, stream>>>(hx, s_all + (size_t)(layer * 2 + 1) * NB * DD, y_bf);
        gemm_geglu_kernel<<<dim3(16, 32), 256, 0, stream>>>(
            y_bf, wupT + (size_t)layer * 1048576, g_bf);
        gemm_bf16_kernel<<<dim3(512 / 128, TOK / 128), 256, 0, stream>>>(
            g_bf, wdownT + (size_t)layer * 524288, hx, hx, TOK, 512, 1024);
    }
    rmsnorm_f32_kernel<<<TOK, 256, 0, stream>>>(hx, out_scale, out);
}

// Round 10
// 678.394 us; speedup vs baseline: 6.0102x; 1.2541x over previous
//
#include <hip/hip_runtime.h>
#include <hip/hip_bf16.h>

#define NB 2
#define LL 2048
#define DD 512
#define HH 8
#define EE 64
#define DFF 1024
#define NL 4
#define EPS_F 1e-6f

typedef __bf16 bf16x8 __attribute__((ext_vector_type(8)));
typedef float f32x4 __attribute__((ext_vector_type(4)));

// round-to-nearest-even f32 -> bf16 bits
__device__ __forceinline__ unsigned short f2bf(float f) {
    unsigned int u = __float_as_uint(f);
    unsigned int r = (u + 0x7FFFu + ((u >> 16) & 1u)) >> 16;
    return (unsigned short)r;
}

// ---------------------------------------------------------------------------
// rope table
// ---------------------------------------------------------------------------
__global__ void rope_table_kernel(float* __restrict__ cosT, float* __restrict__ sinT) {
    int idx = blockIdx.x * 256 + threadIdx.x;
    if (idx >= LL * 32) return;
    int l = idx >> 5, i = idx & 31;
    float inv = powf(10000.f, -(float)i * (1.f / 32.f));
    float ang = (float)l * inv;
    cosT[idx] = cosf(ang);
    sinT[idx] = sinf(ang);
}

// ---------------------------------------------------------------------------
// ALL weight cast+transpose in one dispatch. 10240 blocks of 32x32 tiles.
// ---------------------------------------------------------------------------
__global__ __launch_bounds__(256) void wcast_all_kernel(const float* __restrict__ wqkv,
                                                        const float* __restrict__ wout,
                                                        const float* __restrict__ wup,
                                                        const float* __restrict__ wdown,
                                                        unsigned short* __restrict__ wt) {
    int bid = blockIdx.x;                 // 10240 = 4 layers * 2560 tiles
    int layer = bid / 2560, rem = bid % 2560;
    const float* W; unsigned short* WT; int K, N, t;
    if (rem < 768)       { W = wqkv  + (size_t)layer * 786432;  WT = wt + (size_t)layer * 786432;            K = 512;  N = 1536; t = rem; }
    else if (rem < 1024) { W = wout  + (size_t)layer * 262144;  WT = wt + 3145728 + (size_t)layer * 262144;  K = 512;  N = 512;  t = rem - 768; }
    else if (rem < 2048) { W = wup   + (size_t)layer * 1048576; WT = wt + 4194304 + (size_t)layer * 1048576; K = 512;  N = 2048; t = rem - 1024; }
    else                 { W = wdown + (size_t)layer * 524288;  WT = wt + 8388608 + (size_t)layer * 524288;  K = 1024; N = 512;  t = rem - 2048; }
    int tn = N / 32;
    int n0 = (t % tn) * 32, k0 = (t / tn) * 32;
    __shared__ float tile[32][33];
    int r = threadIdx.x >> 5, c = threadIdx.x & 31;
#pragma unroll
    for (int i = 0; i < 4; ++i)
        tile[r + 8 * i][c] = W[(size_t)(k0 + r + 8 * i) * N + n0 + c];
    __syncthreads();
#pragma unroll
    for (int i = 0; i < 4; ++i)
        WT[(size_t)(n0 + r + 8 * i) * K + k0 + c] = f2bf(tile[c][r + 8 * i]);
}

// ---------------------------------------------------------------------------
// all cond scales in ONE dispatch
// ---------------------------------------------------------------------------
__global__ __launch_bounds__(256) void cond_all_kernel(const float* __restrict__ cond,
                                                       const float* __restrict__ wn_attn,
                                                       const float* __restrict__ wn_ff,
                                                       float* __restrict__ s_all) {
    int bid = blockIdx.x;                 // 128
    int d0 = (bid & 7) * 64;
    int b = (bid >> 3) & 1;
    int which = (bid >> 4) & 1;
    int layer = bid >> 5;
    const float* W = (which ? wn_ff : wn_attn) + (size_t)layer * DD * DD;
    int t = threadIdx.x;
    int d = d0 + (t & 63), kq = t >> 6;
    const float* c = cond + b * DD + kq * 128;
    const float* Wp = W + (size_t)(kq * 128) * DD + d;
    float s = 0.f;
#pragma unroll 8
    for (int j = 0; j < 128; ++j) s = fmaf(c[j], Wp[(size_t)j * DD], s);
    __shared__ float red[4][64];
    red[kq][t & 63] = s;
    __syncthreads();
    if (t < 64) {
        float tot = 1.f + red[0][t] + red[1][t] + red[2][t] + red[3][t];
        s_all[((size_t)(layer * 2 + which) * NB + b) * DD + d0 + t] = tot;
    }
}

// ---------------------------------------------------------------------------
// RMSNorm over D=512, scale (B,D), bf16 output
// ---------------------------------------------------------------------------
__global__ __launch_bounds__(256) void rmsnorm_bf16_kernel(const float* __restrict__ x,
                                                           const float* __restrict__ scale,
                                                           unsigned short* __restrict__ y) {
    int row = blockIdx.x;
    int b = row >> 11;
    int t = threadIdx.x;
    float2 v = ((const float2*)(x + (size_t)row * DD))[t];
    float ss = v.x * v.x + v.y * v.y;
#pragma unroll
    for (int o = 32; o > 0; o >>= 1) ss += __shfl_xor(ss, o);
    __shared__ float red[4];
    if ((t & 63) == 0) red[t >> 6] = ss;
    __syncthreads();
    float tot = red[0] + red[1] + red[2] + red[3];
    float inv = rsqrtf(tot * (1.f / DD) + EPS_F);
    float2 s2 = ((const float2*)(scale + b * DD))[t];
    unsigned int lo = f2bf(v.x * s2.x * inv);
    unsigned int hi = f2bf(v.y * s2.y * inv);
    ((unsigned int*)(y + (size_t)row * DD))[t] = lo | (hi << 16);
}

// RMSNorm, scale (D,), fp32 output (final)
__global__ __launch_bounds__(256) void rmsnorm_f32_kernel(const float* __restrict__ x,
                                                          const float* __restrict__ scale,
                                                          float* __restrict__ y) {
    int row = blockIdx.x;
    int t = threadIdx.x;
    float2 v = ((const float2*)(x + (size_t)row * DD))[t];
    float ss = v.x * v.x + v.y * v.y;
#pragma unroll
    for (int o = 32; o > 0; o >>= 1) ss += __shfl_xor(ss, o);
    __shared__ float red[4];
    if ((t & 63) == 0) red[t >> 6] = ss;
    __syncthreads();
    float tot = red[0] + red[1] + red[2] + red[3];
    float inv = rsqrtf(tot * (1.f / DD) + EPS_F);
    float2 s2 = ((const float2*)scale)[t];
    float2 o2;
    o2.x = v.x * s2.x * inv;
    o2.y = v.y * s2.y * inv;
    ((float2*)(y + (size_t)row * DD))[t] = o2;
}

// ---------------------------------------------------------------------------
// bf16 MFMA GEMM, templated tile width: C = (R?R:0) + A[M,K] @ BT[N,K]^T
// BN=128: 128x128 tile, wave 64x64 (4x4 frags). BN=64: 128x64, wave 64x32.
// ---------------------------------------------------------------------------
#define LDP 40
template <int BN>
__global__ __launch_bounds__(256) void gemm_bf16_kernel(const unsigned short* __restrict__ A,
                                                        const unsigned short* __restrict__ BT,
                                                        const float* __restrict__ R,
                                                        float* __restrict__ C,
                                                        int M, int N, int K) {
    constexpr int NJ = BN / 32;           // b-frags per wave
    __shared__ unsigned short As[128 * LDP];
    __shared__ unsigned short Bs[BN * LDP];
    int tid = threadIdx.x;
    int n0 = blockIdx.x * BN, m0 = blockIdx.y * 128;
    int w = tid >> 6, l = tid & 63;
    int wr = w >> 1, wc = w & 1;
    int kf = 8 * (l >> 4);
    int rf = l & 15;

    f32x4 acc[4][NJ] = {};

    for (int k0 = 0; k0 < K; k0 += 32) {
#pragma unroll
        for (int u2 = 0; u2 < 2; ++u2) {   // A: 512 chunks of 16B
            int c = tid * 2 + u2;
            int row = c >> 2, ch = c & 3;
            *(uint4*)(&As[row * LDP + ch * 8]) =
                *(const uint4*)(A + (size_t)(m0 + row) * K + k0 + ch * 8);
        }
#pragma unroll
        for (int u2 = 0; u2 < BN / 64; ++u2) {   // B: BN*4 chunks
            int c = tid * (BN / 64) + u2;
            int row = c >> 2, ch = c & 3;
            *(uint4*)(&Bs[row * LDP + ch * 8]) =
                *(const uint4*)(BT + (size_t)(n0 + row) * K + k0 + ch * 8);
        }
        __syncthreads();

        bf16x8 a[4], b[NJ];
#pragma unroll
        for (int i = 0; i < 4; ++i)
            a[i] = *(const bf16x8*)(&As[(wr * 64 + i * 16 + rf) * LDP + kf]);
#pragma unroll
        for (int j = 0; j < NJ; ++j)
            b[j] = *(const bf16x8*)(&Bs[(wc * (BN / 2) + j * 16 + rf) * LDP + kf]);
#pragma unroll
        for (int i = 0; i < 4; ++i)
#pragma unroll
            for (int j = 0; j < NJ; ++j)
                acc[i][j] = __builtin_amdgcn_mfma_f32_16x16x32_bf16(a[i], b[j], acc[i][j], 0, 0, 0);
        __syncthreads();
    }

    int rl = l >> 4, cl = l & 15;
#pragma unroll
    for (int i = 0; i < 4; ++i)
#pragma unroll
        for (int j = 0; j < NJ; ++j)
#pragma unroll
            for (int r = 0; r < 4; ++r) {
                int row = m0 + wr * 64 + i * 16 + rl * 4 + r;
                int col = n0 + wc * (BN / 2) + j * 16 + cl;
                size_t off = (size_t)row * N + col;
                float v = acc[i][j][r];
                if (R) v += R[off];
                C[off] = v;
            }
}

// ---------------------------------------------------------------------------
// wup GEMM + fused geglu. Block computes a-cols [n0,n0+64) and b-cols
// [1024+n0, 1024+n0+64); epilogue: g = bf16(a * gelu_exact(b)).
// ---------------------------------------------------------------------------
__global__ __launch_bounds__(256) void gemm_geglu_kernel(const unsigned short* __restrict__ A,
                                                         const unsigned short* __restrict__ BT,
                                                         unsigned short* __restrict__ G) {
    __shared__ unsigned short As[128 * LDP];
    __shared__ unsigned short Bs[128 * LDP];
    __shared__ float ep[128][65];
    int tid = threadIdx.x;
    int n0 = blockIdx.x * 64, m0 = blockIdx.y * 128;
    int w = tid >> 6, l = tid & 63;
    int wr = w >> 1, wc = w & 1;
    int kf = 8 * (l >> 4);
    int rf = l & 15;

    f32x4 acc[4][4] = {};

    for (int k0 = 0; k0 < DD; k0 += 32) {
#pragma unroll
        for (int u2 = 0; u2 < 2; ++u2) {
            int c = tid * 2 + u2;
            int row = c >> 2, ch = c & 3;
            *(uint4*)(&As[row * LDP + ch * 8]) =
                *(const uint4*)(A + (size_t)(m0 + row) * DD + k0 + ch * 8);
            int grow = (row < 64) ? (n0 + row) : (DFF + n0 + row - 64);
            *(uint4*)(&Bs[row * LDP + ch * 8]) =
                *(const uint4*)(BT + (size_t)grow * DD + k0 + ch * 8);
        }
        __syncthreads();

        bf16x8 a[4], b[4];
#pragma unroll
        for (int i = 0; i < 4; ++i)
            a[i] = *(const bf16x8*)(&As[(wr * 64 + i * 16 + rf) * LDP + kf]);
#pragma unroll
        for (int j = 0; j < 4; ++j)
            b[j] = *(const bf16x8*)(&Bs[(wc * 64 + j * 16 + rf) * LDP + kf]);
#pragma unroll
        for (int i = 0; i < 4; ++i)
#pragma unroll
            for (int j = 0; j < 4; ++j)
                acc[i][j] = __builtin_amdgcn_mfma_f32_16x16x32_bf16(a[i], b[j], acc[i][j], 0, 0, 0);
        __syncthreads();
    }

    int rl = l >> 4, cl = l & 15;
    if (wc == 0) {  // a-cols -> LDS
#pragma unroll
        for (int i = 0; i < 4; ++i)
#pragma unroll
            for (int j = 0; j < 4; ++j)
#pragma unroll
                for (int r = 0; r < 4; ++r)
                    ep[wr * 64 + i * 16 + rl * 4 + r][j * 16 + cl] = acc[i][j][r];
    }
    __syncthreads();
    if (wc == 1) {  // b-cols: g = a * gelu(b)
#pragma unroll
        for (int i = 0; i < 4; ++i)
#pragma unroll
            for (int j = 0; j < 4; ++j)
#pragma unroll
                for (int r = 0; r < 4; ++r) {
                    int row = wr * 64 + i * 16 + rl * 4 + r;
                    float bv = acc[i][j][r];
                    float av = ep[row][j * 16 + cl];
                    float ge = 0.5f * bv * (1.f + erff(bv * 0.70710678f));
                    G[(size_t)(m0 + row) * DFF + n0 + j * 16 + cl] = f2bf(av * ge);
                }
    }
}

// ---------------------------------------------------------------------------
// fused qknorm+rope (blocks 0..8191) and V transpose (blocks 8192..8703)
// ---------------------------------------------------------------------------
__global__ __launch_bounds__(256) void qkv_prep_kernel(const float* __restrict__ qkv,
                                                       const float* __restrict__ qs,
                                                       const float* __restrict__ cosT,
                                                       const float* __restrict__ sinT,
                                                       unsigned short* __restrict__ qh,
                                                       unsigned short* __restrict__ kh,
                                                       unsigned short* __restrict__ vt) {
    __shared__ float tile[64][65];
    int t = threadIdx.x;
    if (blockIdx.x < 8192) {
        int w = blockIdx.x * 4 + (t >> 6);   // (b*L + l)*H + h
        int e = t & 63;
        int h = w & 7;
        int l = (w >> 3) & (LL - 1);
        int b = w >> 14;
        size_t rb = ((size_t)(b * LL + l)) * (3 * DD) + h * EE + e;
        float q = qkv[rb];
        float k = qkv[rb + DD];
        float sq = q * q, sk = k * k;
#pragma unroll
        for (int o = 1; o < 64; o <<= 1) {
            sq += __shfl_xor(sq, o);
            sk += __shfl_xor(sk, o);
        }
        float hsc = expf(0.5f * fminf(qs[h], 4.60517019f) - 1.03972077f) * 0.35355339059f;
        float qn = q * hsc * rsqrtf(sq * (1.f / EE) + EPS_F);
        float kn = k * hsc * rsqrtf(sk * (1.f / EE) + EPS_F);
        float qp = __shfl_xor(qn, 32);
        float kp = __shfl_xor(kn, 32);
        int i = e & 31;
        float c = cosT[l * 32 + i], s = sinT[l * 32 + i];
        float qo = (e < 32) ? (qn * c - qp * s) : (qp * s + qn * c);
        float ko = (e < 32) ? (kn * c - kp * s) : (kp * s + kn * c);
        size_t ob = ((size_t)((b * HH + h) * LL + l)) * EE + e;
        qh[ob] = f2bf(qo);
        kh[ob] = f2bf(ko);
    } else {
        int bid = blockIdx.x - 8192;     // 512 = 16 bh * 32 ltiles
        int lt = bid & 31, bh = bid >> 5;
        int b = bh >> 3, h = bh & 7;
        int l0 = lt * 64;
#pragma unroll
        for (int i = 0; i < 4; ++i) {
            int c = t + i * 256;
            int row = c >> 4, q4 = c & 15;
            float4 v4 = *(const float4*)(qkv + ((size_t)(b * LL + l0 + row)) * (3 * DD) + 2 * DD + h * EE + q4 * 4);
            tile[row][q4 * 4 + 0] = v4.x;
            tile[row][q4 * 4 + 1] = v4.y;
            tile[row][q4 * 4 + 2] = v4.z;
            tile[row][q4 * 4 + 3] = v4.w;
        }
        __syncthreads();
        int e = t >> 2, lc = t & 3;
        unsigned int* dst = (unsigned int*)(vt + ((size_t)(bh * EE + e)) * LL + l0 + lc * 16);
#pragma unroll
        for (int j2 = 0; j2 < 8; ++j2) {
            unsigned int lo = f2bf(tile[lc * 16 + 2 * j2][e]);
            unsigned int hi = f2bf(tile[lc * 16 + 2 * j2 + 1][e]);
            dst[j2] = lo | (hi << 16);
        }
    }
}

// ---------------------------------------------------------------------------
// MFMA flash attention v4: no-max softmax (|S|<=10 bound) makes attention
// LINEAR in kv chunks -> KV-split by 2 for 2x occupancy. Each block handles
// 16 kv-tiles, writes unnormalized f32 O-partial + row sums; combine kernel
// merges. Grid 1024 = 4 blocks/CU. Row sums via ones-row MFMA (col 64).
// ---------------------------------------------------------------------------
#define KVB 64
__global__ __launch_bounds__(256) void flash_mfma_kernel(const unsigned short* __restrict__ qh,
                                                         const unsigned short* __restrict__ kh,
                                                         const unsigned short* __restrict__ vt,
                                                         float* __restrict__ op,
                                                         float* __restrict__ os) {
    __shared__ unsigned short K_lds[64 * 72];
    __shared__ unsigned short VT_lds[80 * 72];   // rows 64..79: ones row + zeros
    __shared__ unsigned short P_lds[4][16 * 72];
    int bid = blockIdx.x;            // 1024
    int qb = bid & 31, h = (bid >> 5) & 7, b = (bid >> 8) & 1, split = bid >> 9;
    int bh = b * HH + h;
    int tid = threadIdx.x, w = tid >> 6, l = tid & 63;
    int lo = l & 15, hi4 = l >> 4;
    int q0 = qb * 64 + w * 16;

    // one-time: e=64 row of ones (bf16 1.0 = 0x3F80), rows 65..79 zero.
    for (int idx = tid; idx < 16 * 72; idx += 256) {
        int rr = idx / 72;
        VT_lds[(64 + rr) * 72 + (idx - rr * 72)] = (rr == 0) ? 0x3F80 : 0;
    }

    const unsigned short* qbase = qh + ((size_t)bh * LL) * EE;
    bf16x8 qa[2];
#pragma unroll
    for (int s = 0; s < 2; ++s)
        qa[s] = *(const bf16x8*)(qbase + (size_t)(q0 + lo) * EE + s * 32 + 8 * hi4);

    f32x4 oacc[4] = {};
    f32x4 osum = {};

    for (int kt = split * 16; kt < split * 16 + 16; ++kt) {
        int kv0 = kt * KVB;
#pragma unroll
        for (int u = 0; u < 4; ++u) {
            int c = tid + u * 256;           // 0..1023
            int arr = c >> 9, cc = c & 511;
            int row = cc >> 3, ch = cc & 7;
            if (arr == 0)
                *(uint4*)&K_lds[row * 72 + ch * 8] =
                    *(const uint4*)(kh + ((size_t)bh * LL + kv0 + row) * EE + ch * 8);
            else
                *(uint4*)&VT_lds[row * 72 + ch * 8] =
                    *(const uint4*)(vt + ((size_t)bh * EE + row) * LL + kv0 + ch * 8);
        }
        __syncthreads();

        // S = Q K^T (scale pre-folded)
        f32x4 S[4] = {};
        __builtin_amdgcn_s_setprio(1);
#pragma unroll
        for (int nf = 0; nf < 4; ++nf) {
#pragma unroll
            for (int s = 0; s < 2; ++s) {
                bf16x8 kb = *(const bf16x8*)&K_lds[(nf * 16 + lo) * 72 + s * 32 + 8 * hi4];
                S[nf] = __builtin_amdgcn_mfma_f32_16x16x32_bf16(qa[s], kb, S[nf], 0, 0, 0);
            }
        }
        __builtin_amdgcn_s_setprio(0);

        // P = exp(S) -- no max subtraction needed (S bounded)
#pragma unroll
        for (int r = 0; r < 4; ++r)
#pragma unroll
            for (int nf = 0; nf < 4; ++nf)
                P_lds[w][(hi4 * 4 + r) * 72 + nf * 16 + lo] = f2bf(expf(S[nf][r]));

        // O += P V ; col 64 (ones row) accumulates row sums
        __builtin_amdgcn_s_setprio(1);
#pragma unroll
        for (int s = 0; s < 2; ++s) {
            bf16x8 pa = *(const bf16x8*)&P_lds[w][lo * 72 + s * 32 + 8 * hi4];
#pragma unroll
            for (int nf = 0; nf < 4; ++nf) {
                bf16x8 vb = *(const bf16x8*)&VT_lds[(nf * 16 + lo) * 72 + s * 32 + 8 * hi4];
                oacc[nf] = __builtin_amdgcn_mfma_f32_16x16x32_bf16(pa, vb, oacc[nf], 0, 0, 0);
            }
            bf16x8 vbE = *(const bf16x8*)&VT_lds[(64 + lo) * 72 + s * 32 + 8 * hi4];
            osum = __builtin_amdgcn_mfma_f32_16x16x32_bf16(pa, vbE, osum, 0, 0, 0);
        }
        __builtin_amdgcn_s_setprio(0);
        __syncthreads();
    }

    float* opp = op + (size_t)split * (NB * LL * DD);
#pragma unroll
    for (int r = 0; r < 4; ++r) {
        int row = q0 + hi4 * 4 + r;
        float* optr = opp + ((size_t)(b * LL + row)) * DD + h * EE;
#pragma unroll
        for (int nf = 0; nf < 4; ++nf)
            optr[nf * 16 + lo] = oacc[nf][r];
        if (lo == 0)
            os[split * (NB * HH * LL) + bh * LL + row] = osum[r];
    }
}

// ---------------------------------------------------------------------------
// combine: oh = bf16( (op0+op1) / (s0+s1) ). 2M elements, float4 per thread.
// ---------------------------------------------------------------------------
__global__ __launch_bounds__(256) void attn_combine_kernel(const float* __restrict__ op,
                                                           const float* __restrict__ os,
                                                           unsigned short* __restrict__ oh) {
    int idx = (blockIdx.x * 256 + threadIdx.x) * 4;   // over 2M elems
    int col = idx & 511;
    int h = col >> 6;
    int row = (idx >> 9) & (LL - 1);
    int b = idx >> 20;
    int bh = b * HH + h;
    float s = os[bh * LL + row] + os[NB * HH * LL + bh * LL + row];
    float inv = 1.f / s;
    float4 a = *(const float4*)(op + idx);
    float4 c = *(const float4*)(op + (size_t)(NB * LL * DD) + idx);
    ushort4 o4;
    o4.x = f2bf((a.x + c.x) * inv);
    o4.y = f2bf((a.y + c.y) * inv);
    o4.z = f2bf((a.z + c.z) * inv);
    o4.w = f2bf((a.w + c.w) * inv);
    *(ushort4*)(oh + idx) = o4;
}

// ---------------------------------------------------------------------------
extern "C" void kernel_launch(void* const* d_in, const int* in_sizes, int n_in,
                              void* d_out, int out_size, void* d_ws, size_t ws_size,
                              hipStream_t stream) {
    const float* x        = (const float*)d_in[0];
    const float* cond     = (const float*)d_in[1];
    // d_in[2] attn_mask: bias varies only with query index -> softmax-invariant -> unused
    const float* wn_attn  = (const float*)d_in[3];
    const float* wqkv     = (const float*)d_in[4];
    const float* qk_scale = (const float*)d_in[5];
    const float* wout     = (const float*)d_in[6];
    const float* wn_ff    = (const float*)d_in[7];
    const float* wup      = (const float*)d_in[8];
    const float* wdown    = (const float*)d_in[9];
    const float* out_scale= (const float*)d_in[10];
    float* out = (float*)d_out;

    const int TOK = NB * LL;                 // 4096
    const size_t nHx = (size_t)TOK * DD;     // 2,097,152
    const size_t M = 1024 * 1024;

    float* ws = (float*)d_ws;
    float* hx  = ws;                                   // [0, 2M) f32
    unsigned short* y_bf = (unsigned short*)(ws + 2 * M);      // [2M,3M)
    float* qkv = ws + 3 * M;                           // [3M, 9M) f32 (dead after qkv_prep)
    float* op  = ws + 3 * M;                           // [3M, 7M) f32: 2 splits x 2M (aliases qkv)
    float* os  = ws + 7 * M;                           // [7M, 7M+64K) f32: 2 x 32768
    unsigned short* qh_bf = (unsigned short*)(ws + 11 * M);    // [11M,12M)
    unsigned short* g_bf  = (unsigned short*)(ws + 11 * M);    // [11M,13M) (qh/kh dead by geglu)
    unsigned short* kh_bf = (unsigned short*)(ws + 12 * M);    // [12M,13M)
    unsigned short* vt_bf = (unsigned short*)(ws + 13 * M);    // [13M,14M)
    unsigned short* oh_bf = (unsigned short*)(ws + 14 * M);    // [14M,15M)
    unsigned short* wt = (unsigned short*)(ws + 15 * M);       // [15M,20M)
    float* smal  = ws + 20 * M;
    float* s_all = smal;                      // NL*2*NB*DD = 8192
    float* cosT  = smal + 8192;
    float* sinT  = cosT + 65536;

    hipMemcpyAsync(hx, x, nHx * sizeof(float), hipMemcpyDeviceToDevice, stream);
    rope_table_kernel<<<256, 256, 0, stream>>>(cosT, sinT);
    cond_all_kernel<<<128, 256, 0, stream>>>(cond, wn_attn, wn_ff, s_all);
    wcast_all_kernel<<<10240, 256, 0, stream>>>(wqkv, wout, wup, wdown, wt);

    unsigned short* wqkvT  = wt;
    unsigned short* woutT  = wt + 3145728;
    unsigned short* wupT   = wt + 4194304;
    unsigned short* wdownT = wt + 8388608;

    for (int layer = 0; layer < NL; ++layer) {
        const float* qs = qk_scale + layer * HH;

        rmsnorm_bf16_kernel<<<TOK, 256, 0, stream>>>(hx, s_all + (size_t)(layer * 2 + 0) * NB * DD, y_bf);
        gemm_bf16_kernel<64><<<dim3(1536 / 64, TOK / 128), 256, 0, stream>>>(
            y_bf, wqkvT + (size_t)layer * 786432, nullptr, qkv, TOK, 1536, 512);
        qkv_prep_kernel<<<8704, 256, 0, stream>>>(qkv, qs, cosT, sinT, qh_bf, kh_bf, vt_bf);
        flash_mfma_kernel<<<1024, 256, 0, stream>>>(qh_bf, kh_bf, vt_bf, op, os);
        attn_combine_kernel<<<2048, 256, 0, stream>>>(op, os, oh_bf);
        gemm_bf16_kernel<64><<<dim3(512 / 64, TOK / 128), 256, 0, stream>>>(
            oh_bf, woutT + (size_t)layer * 262144, hx, hx, TOK, 512, 512);

        rmsnorm_bf16_kernel<<<TOK, 256, 0, stream>>>(hx, s_all + (size_t)(layer * 2 + 1) * NB * DD, y_bf);
        gemm_geglu_kernel<<<dim3(16, 32), 256, 0, stream>>>(
            y_bf, wupT + (size_t)layer * 1048576, g_bf);
        gemm_bf16_kernel<64><<<dim3(512 / 64, TOK / 128), 256, 0, stream>>>(
            g_bf, wdownT + (size_t)layer * 524288, hx, hx, TOK, 512, 1024);
    }
    rmsnorm_f32_kernel<<<TOK, 256, 0, stream>>>(hx, out_scale, out);
}

// Round 11
// 651.910 us; speedup vs baseline: 6.2544x; 1.0406x over previous
//
#include <hip/hip_runtime.h>
#include <hip/hip_bf16.h>

#define NB 2
#define LL 2048
#define DD 512
#define HH 8
#define EE 64
#define DFF 1024
#define NL 4
#define EPS_F 1e-6f

typedef __bf16 bf16x8 __attribute__((ext_vector_type(8)));
typedef __bf16 bf16x4 __attribute__((ext_vector_type(4)));
typedef float f32x4 __attribute__((ext_vector_type(4)));

// round-to-nearest-even f32 -> bf16 bits
__device__ __forceinline__ unsigned short f2bf(float f) {
    unsigned int u = __float_as_uint(f);
    unsigned int r = (u + 0x7FFFu + ((u >> 16) & 1u)) >> 16;
    return (unsigned short)r;
}
// truncating f32 -> bf16 bits (positive values; bias cancels in P/sum(P))
__device__ __forceinline__ unsigned short f2bf_t(float f) {
    return (unsigned short)(__float_as_uint(f) >> 16);
}

// ---------------------------------------------------------------------------
// rope table
// ---------------------------------------------------------------------------
__global__ void rope_table_kernel(float* __restrict__ cosT, float* __restrict__ sinT) {
    int idx = blockIdx.x * 256 + threadIdx.x;
    if (idx >= LL * 32) return;
    int l = idx >> 5, i = idx & 31;
    float inv = powf(10000.f, -(float)i * (1.f / 32.f));
    float ang = (float)l * inv;
    cosT[idx] = cosf(ang);
    sinT[idx] = sinf(ang);
}

// ---------------------------------------------------------------------------
// ALL weight cast+transpose in one dispatch. 10240 blocks of 32x32 tiles.
// ---------------------------------------------------------------------------
__global__ __launch_bounds__(256) void wcast_all_kernel(const float* __restrict__ wqkv,
                                                        const float* __restrict__ wout,
                                                        const float* __restrict__ wup,
                                                        const float* __restrict__ wdown,
                                                        unsigned short* __restrict__ wt) {
    int bid = blockIdx.x;                 // 10240 = 4 layers * 2560 tiles
    int layer = bid / 2560, rem = bid % 2560;
    const float* W; unsigned short* WT; int K, N, t;
    if (rem < 768)       { W = wqkv  + (size_t)layer * 786432;  WT = wt + (size_t)layer * 786432;            K = 512;  N = 1536; t = rem; }
    else if (rem < 1024) { W = wout  + (size_t)layer * 262144;  WT = wt + 3145728 + (size_t)layer * 262144;  K = 512;  N = 512;  t = rem - 768; }
    else if (rem < 2048) { W = wup   + (size_t)layer * 1048576; WT = wt + 4194304 + (size_t)layer * 1048576; K = 512;  N = 2048; t = rem - 1024; }
    else                 { W = wdown + (size_t)layer * 524288;  WT = wt + 8388608 + (size_t)layer * 524288;  K = 1024; N = 512;  t = rem - 2048; }
    int tn = N / 32;
    int n0 = (t % tn) * 32, k0 = (t / tn) * 32;
    __shared__ float tile[32][33];
    int r = threadIdx.x >> 5, c = threadIdx.x & 31;
#pragma unroll
    for (int i = 0; i < 4; ++i)
        tile[r + 8 * i][c] = W[(size_t)(k0 + r + 8 * i) * N + n0 + c];
    __syncthreads();
#pragma unroll
    for (int i = 0; i < 4; ++i)
        WT[(size_t)(n0 + r + 8 * i) * K + k0 + c] = f2bf(tile[c][r + 8 * i]);
}

// ---------------------------------------------------------------------------
// all cond scales in ONE dispatch
// ---------------------------------------------------------------------------
__global__ __launch_bounds__(256) void cond_all_kernel(const float* __restrict__ cond,
                                                       const float* __restrict__ wn_attn,
                                                       const float* __restrict__ wn_ff,
                                                       float* __restrict__ s_all) {
    int bid = blockIdx.x;                 // 128
    int d0 = (bid & 7) * 64;
    int b = (bid >> 3) & 1;
    int which = (bid >> 4) & 1;
    int layer = bid >> 5;
    const float* W = (which ? wn_ff : wn_attn) + (size_t)layer * DD * DD;
    int t = threadIdx.x;
    int d = d0 + (t & 63), kq = t >> 6;
    const float* c = cond + b * DD + kq * 128;
    const float* Wp = W + (size_t)(kq * 128) * DD + d;
    float s = 0.f;
#pragma unroll 8
    for (int j = 0; j < 128; ++j) s = fmaf(c[j], Wp[(size_t)j * DD], s);
    __shared__ float red[4][64];
    red[kq][t & 63] = s;
    __syncthreads();
    if (t < 64) {
        float tot = 1.f + red[0][t] + red[1][t] + red[2][t] + red[3][t];
        s_all[((size_t)(layer * 2 + which) * NB + b) * DD + d0 + t] = tot;
    }
}

// ---------------------------------------------------------------------------
// RMSNorm over D=512, scale (B,D), bf16 output
// ---------------------------------------------------------------------------
__global__ __launch_bounds__(256) void rmsnorm_bf16_kernel(const float* __restrict__ x,
                                                           const float* __restrict__ scale,
                                                           unsigned short* __restrict__ y) {
    int row = blockIdx.x;
    int b = row >> 11;
    int t = threadIdx.x;
    float2 v = ((const float2*)(x + (size_t)row * DD))[t];
    float ss = v.x * v.x + v.y * v.y;
#pragma unroll
    for (int o = 32; o > 0; o >>= 1) ss += __shfl_xor(ss, o);
    __shared__ float red[4];
    if ((t & 63) == 0) red[t >> 6] = ss;
    __syncthreads();
    float tot = red[0] + red[1] + red[2] + red[3];
    float inv = rsqrtf(tot * (1.f / DD) + EPS_F);
    float2 s2 = ((const float2*)(scale + b * DD))[t];
    unsigned int lo = f2bf(v.x * s2.x * inv);
    unsigned int hi = f2bf(v.y * s2.y * inv);
    ((unsigned int*)(y + (size_t)row * DD))[t] = lo | (hi << 16);
}

// RMSNorm, scale (D,), fp32 output (final)
__global__ __launch_bounds__(256) void rmsnorm_f32_kernel(const float* __restrict__ x,
                                                          const float* __restrict__ scale,
                                                          float* __restrict__ y) {
    int row = blockIdx.x;
    int t = threadIdx.x;
    float2 v = ((const float2*)(x + (size_t)row * DD))[t];
    float ss = v.x * v.x + v.y * v.y;
#pragma unroll
    for (int o = 32; o > 0; o >>= 1) ss += __shfl_xor(ss, o);
    __shared__ float red[4];
    if ((t & 63) == 0) red[t >> 6] = ss;
    __syncthreads();
    float tot = red[0] + red[1] + red[2] + red[3];
    float inv = rsqrtf(tot * (1.f / DD) + EPS_F);
    float2 s2 = ((const float2*)scale)[t];
    float2 o2;
    o2.x = v.x * s2.x * inv;
    o2.y = v.y * s2.y * inv;
    ((float2*)(y + (size_t)row * DD))[t] = o2;
}

// ---------------------------------------------------------------------------
// bf16 MFMA GEMM, templated tile width: C = (R?R:0) + A[M,K] @ BT[N,K]^T
// ---------------------------------------------------------------------------
#define LDP 40
template <int BN>
__global__ __launch_bounds__(256) void gemm_bf16_kernel(const unsigned short* __restrict__ A,
                                                        const unsigned short* __restrict__ BT,
                                                        const float* __restrict__ R,
                                                        float* __restrict__ C,
                                                        int M, int N, int K) {
    constexpr int NJ = BN / 32;           // b-frags per wave
    __shared__ unsigned short As[128 * LDP];
    __shared__ unsigned short Bs[BN * LDP];
    int tid = threadIdx.x;
    int n0 = blockIdx.x * BN, m0 = blockIdx.y * 128;
    int w = tid >> 6, l = tid & 63;
    int wr = w >> 1, wc = w & 1;
    int kf = 8 * (l >> 4);
    int rf = l & 15;

    f32x4 acc[4][NJ] = {};

    for (int k0 = 0; k0 < K; k0 += 32) {
#pragma unroll
        for (int u2 = 0; u2 < 2; ++u2) {   // A: 512 chunks of 16B
            int c = tid * 2 + u2;
            int row = c >> 2, ch = c & 3;
            *(uint4*)(&As[row * LDP + ch * 8]) =
                *(const uint4*)(A + (size_t)(m0 + row) * K + k0 + ch * 8);
        }
#pragma unroll
        for (int u2 = 0; u2 < BN / 64; ++u2) {   // B: BN*4 chunks
            int c = tid * (BN / 64) + u2;
            int row = c >> 2, ch = c & 3;
            *(uint4*)(&Bs[row * LDP + ch * 8]) =
                *(const uint4*)(BT + (size_t)(n0 + row) * K + k0 + ch * 8);
        }
        __syncthreads();

        bf16x8 a[4], b[NJ];
#pragma unroll
        for (int i = 0; i < 4; ++i)
            a[i] = *(const bf16x8*)(&As[(wr * 64 + i * 16 + rf) * LDP + kf]);
#pragma unroll
        for (int j = 0; j < NJ; ++j)
            b[j] = *(const bf16x8*)(&Bs[(wc * (BN / 2) + j * 16 + rf) * LDP + kf]);
#pragma unroll
        for (int i = 0; i < 4; ++i)
#pragma unroll
            for (int j = 0; j < NJ; ++j)
                acc[i][j] = __builtin_amdgcn_mfma_f32_16x16x32_bf16(a[i], b[j], acc[i][j], 0, 0, 0);
        __syncthreads();
    }

    int rl = l >> 4, cl = l & 15;
#pragma unroll
    for (int i = 0; i < 4; ++i)
#pragma unroll
        for (int j = 0; j < NJ; ++j)
#pragma unroll
            for (int r = 0; r < 4; ++r) {
                int row = m0 + wr * 64 + i * 16 + rl * 4 + r;
                int col = n0 + wc * (BN / 2) + j * 16 + cl;
                size_t off = (size_t)row * N + col;
                float v = acc[i][j][r];
                if (R) v += R[off];
                C[off] = v;
            }
}

// ---------------------------------------------------------------------------
// wup GEMM + fused geglu
// ---------------------------------------------------------------------------
__global__ __launch_bounds__(256) void gemm_geglu_kernel(const unsigned short* __restrict__ A,
                                                         const unsigned short* __restrict__ BT,
                                                         unsigned short* __restrict__ G) {
    __shared__ unsigned short As[128 * LDP];
    __shared__ unsigned short Bs[128 * LDP];
    __shared__ float ep[128][65];
    int tid = threadIdx.x;
    int n0 = blockIdx.x * 64, m0 = blockIdx.y * 128;
    int w = tid >> 6, l = tid & 63;
    int wr = w >> 1, wc = w & 1;
    int kf = 8 * (l >> 4);
    int rf = l & 15;

    f32x4 acc[4][4] = {};

    for (int k0 = 0; k0 < DD; k0 += 32) {
#pragma unroll
        for (int u2 = 0; u2 < 2; ++u2) {
            int c = tid * 2 + u2;
            int row = c >> 2, ch = c & 3;
            *(uint4*)(&As[row * LDP + ch * 8]) =
                *(const uint4*)(A + (size_t)(m0 + row) * DD + k0 + ch * 8);
            int grow = (row < 64) ? (n0 + row) : (DFF + n0 + row - 64);
            *(uint4*)(&Bs[row * LDP + ch * 8]) =
                *(const uint4*)(BT + (size_t)grow * DD + k0 + ch * 8);
        }
        __syncthreads();

        bf16x8 a[4], b[4];
#pragma unroll
        for (int i = 0; i < 4; ++i)
            a[i] = *(const bf16x8*)(&As[(wr * 64 + i * 16 + rf) * LDP + kf]);
#pragma unroll
        for (int j = 0; j < 4; ++j)
            b[j] = *(const bf16x8*)(&Bs[(wc * 64 + j * 16 + rf) * LDP + kf]);
#pragma unroll
        for (int i = 0; i < 4; ++i)
#pragma unroll
            for (int j = 0; j < 4; ++j)
                acc[i][j] = __builtin_amdgcn_mfma_f32_16x16x32_bf16(a[i], b[j], acc[i][j], 0, 0, 0);
        __syncthreads();
    }

    int rl = l >> 4, cl = l & 15;
    if (wc == 0) {  // a-cols -> LDS
#pragma unroll
        for (int i = 0; i < 4; ++i)
#pragma unroll
            for (int j = 0; j < 4; ++j)
#pragma unroll
                for (int r = 0; r < 4; ++r)
                    ep[wr * 64 + i * 16 + rl * 4 + r][j * 16 + cl] = acc[i][j][r];
    }
    __syncthreads();
    if (wc == 1) {  // b-cols: g = a * gelu(b)
#pragma unroll
        for (int i = 0; i < 4; ++i)
#pragma unroll
            for (int j = 0; j < 4; ++j)
#pragma unroll
                for (int r = 0; r < 4; ++r) {
                    int row = wr * 64 + i * 16 + rl * 4 + r;
                    float bv = acc[i][j][r];
                    float av = ep[row][j * 16 + cl];
                    float ge = 0.5f * bv * (1.f + erff(bv * 0.70710678f));
                    G[(size_t)(m0 + row) * DFF + n0 + j * 16 + cl] = f2bf(av * ge);
                }
    }
}

// ---------------------------------------------------------------------------
// fused qknorm+rope (blocks 0..8191) and V transpose (blocks 8192..8703).
// q additionally scaled by log2(e) so flash can use exp2 directly.
// ---------------------------------------------------------------------------
__global__ __launch_bounds__(256) void qkv_prep_kernel(const float* __restrict__ qkv,
                                                       const float* __restrict__ qs,
                                                       const float* __restrict__ cosT,
                                                       const float* __restrict__ sinT,
                                                       unsigned short* __restrict__ qh,
                                                       unsigned short* __restrict__ kh,
                                                       unsigned short* __restrict__ vt) {
    __shared__ float tile[64][65];
    int t = threadIdx.x;
    if (blockIdx.x < 8192) {
        int w = blockIdx.x * 4 + (t >> 6);   // (b*L + l)*H + h
        int e = t & 63;
        int h = w & 7;
        int l = (w >> 3) & (LL - 1);
        int b = w >> 14;
        size_t rb = ((size_t)(b * LL + l)) * (3 * DD) + h * EE + e;
        float q = qkv[rb];
        float k = qkv[rb + DD];
        float sq = q * q, sk = k * k;
#pragma unroll
        for (int o = 1; o < 64; o <<= 1) {
            sq += __shfl_xor(sq, o);
            sk += __shfl_xor(sk, o);
        }
        float hsc = expf(0.5f * fminf(qs[h], 4.60517019f) - 1.03972077f) * 0.35355339059f;
        float qn = q * (hsc * 1.44269504f) * rsqrtf(sq * (1.f / EE) + EPS_F);  // fold log2(e)
        float kn = k * hsc * rsqrtf(sk * (1.f / EE) + EPS_F);
        float qp = __shfl_xor(qn, 32);
        float kp = __shfl_xor(kn, 32);
        int i = e & 31;
        float c = cosT[l * 32 + i], s = sinT[l * 32 + i];
        float qo = (e < 32) ? (qn * c - qp * s) : (qp * s + qn * c);
        float ko = (e < 32) ? (kn * c - kp * s) : (kp * s + kn * c);
        size_t ob = ((size_t)((b * HH + h) * LL + l)) * EE + e;
        qh[ob] = f2bf(qo);
        kh[ob] = f2bf(ko);
    } else {
        int bid = blockIdx.x - 8192;     // 512 = 16 bh * 32 ltiles
        int lt = bid & 31, bh = bid >> 5;
        int b = bh >> 3, h = bh & 7;
        int l0 = lt * 64;
#pragma unroll
        for (int i = 0; i < 4; ++i) {
            int c = t + i * 256;
            int row = c >> 4, q4 = c & 15;
            float4 v4 = *(const float4*)(qkv + ((size_t)(b * LL + l0 + row)) * (3 * DD) + 2 * DD + h * EE + q4 * 4);
            tile[row][q4 * 4 + 0] = v4.x;
            tile[row][q4 * 4 + 1] = v4.y;
            tile[row][q4 * 4 + 2] = v4.z;
            tile[row][q4 * 4 + 3] = v4.w;
        }
        __syncthreads();
        int e = t >> 2, lc = t & 3;
        unsigned int* dst = (unsigned int*)(vt + ((size_t)(bh * EE + e)) * LL + l0 + lc * 16);
#pragma unroll
        for (int j2 = 0; j2 < 8; ++j2) {
            unsigned int lo = f2bf(tile[lc * 16 + 2 * j2][e]);
            unsigned int hi = f2bf(tile[lc * 16 + 2 * j2 + 1][e]);
            dst[j2] = lo | (hi << 16);
        }
    }
}

// ---------------------------------------------------------------------------
// MFMA flash attention v5: KVB=32, KV-split x4 (grid 2048, ~8 blocks/CU).
// No-max softmax via exp2 (log2e pre-folded into q). P_lds row stride 36
// ushorts -> conflict-free b16 writes ({0,8,16,24} bank-group spread);
// reads as 2x bf16x4 (8B aligned). Row sums via ones-row MFMA.
// ---------------------------------------------------------------------------
#define KVB 32
#define KLDP 72
#define VLDP 40
#define PLDP 36
__global__ __launch_bounds__(256) void flash_mfma_kernel(const unsigned short* __restrict__ qh,
                                                         const unsigned short* __restrict__ kh,
                                                         const unsigned short* __restrict__ vt,
                                                         float* __restrict__ op,
                                                         float* __restrict__ os) {
    __shared__ unsigned short K_lds[32 * KLDP];       // [kv][e]
    __shared__ unsigned short VT_lds[80 * VLDP];      // [e][kv], rows 64..79 ones/zeros
    __shared__ unsigned short P_lds[4][16 * PLDP];    // [q][kv] per wave
    int bid = blockIdx.x;            // 2048
    int qb = bid & 31, h = (bid >> 5) & 7, b = (bid >> 8) & 1, split = bid >> 9;
    int bh = b * HH + h;
    int tid = threadIdx.x, w = tid >> 6, l = tid & 63;
    int lo = l & 15, hi4 = l >> 4;
    int q0 = qb * 64 + w * 16;

    // one-time: e=64 row of ones (bf16 1.0 = 0x3F80), rows 65..79 zero.
    for (int idx = tid; idx < 16 * VLDP; idx += 256) {
        int rr = idx / VLDP;
        VT_lds[(64 + rr) * VLDP + (idx - rr * VLDP)] = (rr == 0) ? 0x3F80 : 0;
    }

    const unsigned short* qbase = qh + ((size_t)bh * LL) * EE;
    bf16x8 qa[2];
#pragma unroll
    for (int s = 0; s < 2; ++s)
        qa[s] = *(const bf16x8*)(qbase + (size_t)(q0 + lo) * EE + s * 32 + 8 * hi4);

    f32x4 oacc[4] = {};
    f32x4 osum = {};

    for (int kt = split * 16; kt < split * 16 + 16; ++kt) {
        int kv0 = kt * KVB;
#pragma unroll
        for (int u = 0; u < 2; ++u) {
            int c = tid + u * 256;           // 0..511 chunks of 16B
            int arr = c >> 8, cc = c & 255;
            if (arr == 0) {                  // K: 32 rows x 8 chunks
                int row = cc >> 3, ch = cc & 7;
                *(uint4*)&K_lds[row * KLDP + ch * 8] =
                    *(const uint4*)(kh + ((size_t)bh * LL + kv0 + row) * EE + ch * 8);
            } else {                         // VT: 64 rows x 4 chunks
                int row = cc >> 2, ch = cc & 3;
                *(uint4*)&VT_lds[row * VLDP + ch * 8] =
                    *(const uint4*)(vt + ((size_t)bh * EE + row) * LL + kv0 + ch * 8);
            }
        }
        __syncthreads();

        // S = Q K^T (scales pre-folded; S in log2 domain)
        f32x4 S[2] = {};
        __builtin_amdgcn_s_setprio(1);
#pragma unroll
        for (int nf = 0; nf < 2; ++nf)
#pragma unroll
            for (int s = 0; s < 2; ++s) {
                bf16x8 kb = *(const bf16x8*)&K_lds[(nf * 16 + lo) * KLDP + s * 32 + 8 * hi4];
                S[nf] = __builtin_amdgcn_mfma_f32_16x16x32_bf16(qa[s], kb, S[nf], 0, 0, 0);
            }
        __builtin_amdgcn_s_setprio(0);

        // P = exp2(S), truncating bf16 store (conflict-free b16 writes)
#pragma unroll
        for (int r = 0; r < 4; ++r)
#pragma unroll
            for (int nf = 0; nf < 2; ++nf)
                P_lds[w][(hi4 * 4 + r) * PLDP + nf * 16 + lo] = f2bf_t(exp2f(S[nf][r]));

        // O += P V ; ones-row (e=64) accumulates row sums in osum col 0
        __builtin_amdgcn_s_setprio(1);
        bf16x4 p0 = *(const bf16x4*)&P_lds[w][lo * PLDP + 8 * hi4];
        bf16x4 p1 = *(const bf16x4*)&P_lds[w][lo * PLDP + 8 * hi4 + 4];
        bf16x8 pa;
#pragma unroll
        for (int j = 0; j < 4; ++j) { pa[j] = p0[j]; pa[4 + j] = p1[j]; }
#pragma unroll
        for (int nf = 0; nf < 4; ++nf) {
            bf16x8 vb = *(const bf16x8*)&VT_lds[(nf * 16 + lo) * VLDP + 8 * hi4];
            oacc[nf] = __builtin_amdgcn_mfma_f32_16x16x32_bf16(pa, vb, oacc[nf], 0, 0, 0);
        }
        bf16x8 vbE = *(const bf16x8*)&VT_lds[(64 + lo) * VLDP + 8 * hi4];
        osum = __builtin_amdgcn_mfma_f32_16x16x32_bf16(pa, vbE, osum, 0, 0, 0);
        __builtin_amdgcn_s_setprio(0);
        __syncthreads();
    }

    float* opp = op + (size_t)split * (NB * LL * DD);
#pragma unroll
    for (int r = 0; r < 4; ++r) {
        int row = q0 + hi4 * 4 + r;
        float* optr = opp + ((size_t)(b * LL + row)) * DD + h * EE;
#pragma unroll
        for (int nf = 0; nf < 4; ++nf)
            optr[nf * 16 + lo] = oacc[nf][r];
        if (lo == 0)
            os[split * (NB * HH * LL) + bh * LL + row] = osum[r];
    }
}

// ---------------------------------------------------------------------------
// combine 4 partials: oh = bf16( sum_sp op[sp] / sum_sp s[sp] )
// ---------------------------------------------------------------------------
__global__ __launch_bounds__(256) void attn_combine_kernel(const float* __restrict__ op,
                                                           const float* __restrict__ os,
                                                           unsigned short* __restrict__ oh) {
    int idx = (blockIdx.x * 256 + threadIdx.x) * 4;   // over 2M elems
    int col = idx & 511;
    int h = col >> 6;
    int row = (idx >> 9) & (LL - 1);
    int b = idx >> 20;
    int bh = b * HH + h;
    float s = 0.f;
    float4 a = make_float4(0.f, 0.f, 0.f, 0.f);
#pragma unroll
    for (int sp = 0; sp < 4; ++sp) {
        s += os[sp * (NB * HH * LL) + bh * LL + row];
        float4 t = *(const float4*)(op + (size_t)sp * (NB * LL * DD) + idx);
        a.x += t.x; a.y += t.y; a.z += t.z; a.w += t.w;
    }
    float inv = 1.f / s;
    ushort4 o4;
    o4.x = f2bf(a.x * inv);
    o4.y = f2bf(a.y * inv);
    o4.z = f2bf(a.z * inv);
    o4.w = f2bf(a.w * inv);
    *(ushort4*)(oh + idx) = o4;
}

// ---------------------------------------------------------------------------
extern "C" void kernel_launch(void* const* d_in, const int* in_sizes, int n_in,
                              void* d_out, int out_size, void* d_ws, size_t ws_size,
                              hipStream_t stream) {
    const float* x        = (const float*)d_in[0];
    const float* cond     = (const float*)d_in[1];
    // d_in[2] attn_mask: bias varies only with query index -> softmax-invariant -> unused
    const float* wn_attn  = (const float*)d_in[3];
    const float* wqkv     = (const float*)d_in[4];
    const float* qk_scale = (const float*)d_in[5];
    const float* wout     = (const float*)d_in[6];
    const float* wn_ff    = (const float*)d_in[7];
    const float* wup      = (const float*)d_in[8];
    const float* wdown    = (const float*)d_in[9];
    const float* out_scale= (const float*)d_in[10];
    float* out = (float*)d_out;

    const int TOK = NB * LL;                 // 4096
    const size_t nHx = (size_t)TOK * DD;     // 2,097,152
    const size_t M = 1024 * 1024;

    float* ws = (float*)d_ws;
    float* hx  = ws;                                   // [0, 2M) f32
    unsigned short* y_bf = (unsigned short*)(ws + 2 * M);      // [2M,3M)
    float* qkv = ws + 3 * M;                           // [3M, 9M) f32 (dead after qkv_prep)
    float* op  = ws + 3 * M;                           // [3M, 11M): 4 splits x 2M f32 (aliases qkv)
    unsigned short* qh_bf = (unsigned short*)(ws + 11 * M);    // [11M,12M)
    unsigned short* g_bf  = (unsigned short*)(ws + 11 * M);    // [11M,13M) (qh/kh dead by geglu)
    unsigned short* kh_bf = (unsigned short*)(ws + 12 * M);    // [12M,13M)
    unsigned short* vt_bf = (unsigned short*)(ws + 13 * M);    // [13M,14M)
    unsigned short* oh_bf = (unsigned short*)(ws + 14 * M);    // [14M,15M)
    unsigned short* wt = (unsigned short*)(ws + 15 * M);       // [15M,20M)
    float* smal  = ws + 20 * M;
    float* s_all = smal;                      // 8192
    float* os    = smal + 8192;               // 4 x 32768 = 131072
    float* cosT  = os + 131072;
    float* sinT  = cosT + 65536;

    hipMemcpyAsync(hx, x, nHx * sizeof(float), hipMemcpyDeviceToDevice, stream);
    rope_table_kernel<<<256, 256, 0, stream>>>(cosT, sinT);
    cond_all_kernel<<<128, 256, 0, stream>>>(cond, wn_attn, wn_ff, s_all);
    wcast_all_kernel<<<10240, 256, 0, stream>>>(wqkv, wout, wup, wdown, wt);

    unsigned short* wqkvT  = wt;
    unsigned short* woutT  = wt + 3145728;
    unsigned short* wupT   = wt + 4194304;
    unsigned short* wdownT = wt + 8388608;

    for (int layer = 0; layer < NL; ++layer) {
        const float* qs = qk_scale + layer * HH;

        rmsnorm_bf16_kernel<<<TOK, 256, 0, stream>>>(hx, s_all + (size_t)(layer * 2 + 0) * NB * DD, y_bf);
        gemm_bf16_kernel<64><<<dim3(1536 / 64, TOK / 128), 256, 0, stream>>>(
            y_bf, wqkvT + (size_t)layer * 786432, nullptr, qkv, TOK, 1536, 512);
        qkv_prep_kernel<<<8704, 256, 0, stream>>>(qkv, qs, cosT, sinT, qh_bf, kh_bf, vt_bf);
        flash_mfma_kernel<<<2048, 256, 0, stream>>>(qh_bf, kh_bf, vt_bf, op, os);
        attn_combine_kernel<<<2048, 256, 0, stream>>>(op, os, oh_bf);
        gemm_bf16_kernel<64><<<dim3(512 / 64, TOK / 128), 256, 0, stream>>>(
            oh_bf, woutT + (size_t)layer * 262144, hx, hx, TOK, 512, 512);

        rmsnorm_bf16_kernel<<<TOK, 256, 0, stream>>>(hx, s_all + (size_t)(layer * 2 + 1) * NB * DD, y_bf);
        gemm_geglu_kernel<<<dim3(16, 32), 256, 0, stream>>>(
            y_bf, wupT + (size_t)layer * 1048576, g_bf);
        gemm_bf16_kernel<64><<<dim3(512 / 64, TOK / 128), 256, 0, stream>>>(
            g_bf, wdownT + (size_t)layer * 524288, hx, hx, TOK, 512, 1024);
    }
    rmsnorm_f32_kernel<<<TOK, 256, 0, stream>>>(hx, out_scale, out);
}